// Round 8
// baseline (48.122 us; speedup 1.0000x reference)
//
#include <hip/hip_runtime.h>
#include <math.h>

#define NKP 68
#define NB 16
#define SK_ITERS 50
#define NBLK (16 + NB * 64)            // 1040 blocks total

#define INVV 0.03125f                  // 1/(2*sigma^2), sigma=4
#define LOG_A (-4.219507705176107f)    // -log(68)
#define L2E 1.4426950408889634f
#define LN2 0.6931471805599453f
#define KGF (100.0f * L2E)             // (1/eps)*log2(e)
#define SW 40.0f                       // power-of-two shift baked into W
#define WBIAS (L2E * LOG_A + SW)
#define C2X (-INVV * 1.4426950408889634f)  // gaussian exponent, base-2

// workspace float offsets (partials are plain stores; counter memset per call)
#define WS_COST 0     // [16]   sinkhorn per-batch cost
#define WS_BCE0 16    // [1024] per-block bce partial sums
#define WS_CNT  1056  // [1]    int completion counter

typedef float f32x2 __attribute__((ext_vector_type(2)));

__device__ __forceinline__ float E2(float x) {
#if __has_builtin(__builtin_amdgcn_exp2f)
  return __builtin_amdgcn_exp2f(x);
#else
  return exp2f(x);
#endif
}
__device__ __forceinline__ float L2(float x) {
#if __has_builtin(__builtin_amdgcn_logf)
  return __builtin_amdgcn_logf(x);   // v_log_f32 = log2
#else
  return log2f(x);
#endif
}
__device__ __forceinline__ float RCP(float x) {
#if __has_builtin(__builtin_amdgcn_rcpf)
  return __builtin_amdgcn_rcpf(x);   // v_rcp_f32, ~1 ulp
#else
  return 1.0f / x;
#endif
}
__device__ __forceinline__ f32x2 fma2(f32x2 a, f32x2 b, f32x2 c) {
#if __has_builtin(__builtin_elementwise_fma)
  return __builtin_elementwise_fma(a, b, c);   // -> v_pk_fma_f32
#else
  f32x2 r; r.x = fmaf(a.x, b.x, c.x); r.y = fmaf(a.y, b.y, c.y); return r;
#endif
}
// sum over a quad (DPP quad_perm xor1 + xor2) — all 4 lanes get the total
__device__ __forceinline__ float quad_sum(float s) {
#if __has_builtin(__builtin_amdgcn_mov_dpp)
  int a = __builtin_amdgcn_mov_dpp(__float_as_int(s), 0xB1, 0xF, 0xF, true);
  s += __int_as_float(a);
  int b2 = __builtin_amdgcn_mov_dpp(__float_as_int(s), 0x4E, 0xF, 0xF, true);
  s += __int_as_float(b2);
  return s;
#else
  s += __shfl_xor(s, 1);
  s += __shfl_xor(s, 2);
  return s;
#endif
}
// W_ij = 2^40 * exp(-C_ij/eps)/N, computed in base 2
__device__ __forceinline__ float wcomp(float2 a, float2 b) {
  float d0 = a.x - b.x, d1 = a.y - b.y;
  return E2(fmaf(-KGF, d0 * d0 + d1 * d1, WBIAS));
}

// ---------------------------------------------------------------------------
// Sinkhorn, SINGLE WAVE per batch, barrier-free.
// Lane = 4*rs + cq: quad rs owns rows {rs,rs+16,rs+32,rs+48,(64+rs if rs<4)},
// col-quarter cq owns logical columns [17cq,17cq+17) (LDS padded groups of 20).
// Per half-update: broadcast ds_read of v-slice, 5 packed-FMA row dots,
// quad DPP reduce, v_rcp, predicated ds_write. No s_barrier anywhere.
// ---------------------------------------------------------------------------
#define DECLW_F(P, XP)                                                        \
  const f32x2 wf##P##_0 = {wcomp(XP, tc[c0+ 0]), wcomp(XP, tc[c0+ 1])};       \
  const f32x2 wf##P##_1 = {wcomp(XP, tc[c0+ 2]), wcomp(XP, tc[c0+ 3])};       \
  const f32x2 wf##P##_2 = {wcomp(XP, tc[c0+ 4]), wcomp(XP, tc[c0+ 5])};       \
  const f32x2 wf##P##_3 = {wcomp(XP, tc[c0+ 6]), wcomp(XP, tc[c0+ 7])};       \
  const f32x2 wf##P##_4 = {wcomp(XP, tc[c0+ 8]), wcomp(XP, tc[c0+ 9])};       \
  const f32x2 wf##P##_5 = {wcomp(XP, tc[c0+10]), wcomp(XP, tc[c0+11])};       \
  const f32x2 wf##P##_6 = {wcomp(XP, tc[c0+12]), wcomp(XP, tc[c0+13])};       \
  const f32x2 wf##P##_7 = {wcomp(XP, tc[c0+14]), wcomp(XP, tc[c0+15])};       \
  const float wf##P##_s = wcomp(XP, tc[c0+16]);

#define DECLW_G(P, YP)                                                        \
  const f32x2 wg##P##_0 = {wcomp(pc[c0+ 0], YP), wcomp(pc[c0+ 1], YP)};       \
  const f32x2 wg##P##_1 = {wcomp(pc[c0+ 2], YP), wcomp(pc[c0+ 3], YP)};       \
  const f32x2 wg##P##_2 = {wcomp(pc[c0+ 4], YP), wcomp(pc[c0+ 5], YP)};       \
  const f32x2 wg##P##_3 = {wcomp(pc[c0+ 6], YP), wcomp(pc[c0+ 7], YP)};       \
  const f32x2 wg##P##_4 = {wcomp(pc[c0+ 8], YP), wcomp(pc[c0+ 9], YP)};       \
  const f32x2 wg##P##_5 = {wcomp(pc[c0+10], YP), wcomp(pc[c0+11], YP)};       \
  const f32x2 wg##P##_6 = {wcomp(pc[c0+12], YP), wcomp(pc[c0+13], YP)};       \
  const f32x2 wg##P##_7 = {wcomp(pc[c0+14], YP), wcomp(pc[c0+15], YP)};       \
  const float wg##P##_s = wcomp(pc[c0+16], YP);

#define LOADV(SRC)                                                            \
    const f32x2* vv = (const f32x2*)&SRC[rb];                                 \
    const f32x2 V0 = vv[0], V1 = vv[1], V2 = vv[2], V3 = vv[3];               \
    const f32x2 V4 = vv[4], V5 = vv[5], V6 = vv[6], V7 = vv[7];               \
    const float VS = SRC[rb + 16];

#define DOT17(PFX, RES)                                                       \
  { f32x2 A = PFX##_0 * V0;                                                   \
    A = fma2(PFX##_1, V1, A);                                                 \
    A = fma2(PFX##_2, V2, A);                                                 \
    A = fma2(PFX##_3, V3, A);                                                 \
    A = fma2(PFX##_4, V4, A);                                                 \
    A = fma2(PFX##_5, V5, A);                                                 \
    A = fma2(PFX##_6, V6, A);                                                 \
    A = fma2(PFX##_7, V7, A);                                                 \
    RES = fmaf(PFX##_s, VS, A.x + A.y); }

#define HALF(SRC, DST, WPFX, U0, U1, U2, U3, U4)                              \
  { LOADV(SRC)                                                                \
    float s0, s1, s2, s3, s4;                                                 \
    DOT17(WPFX##0, s0) DOT17(WPFX##1, s1) DOT17(WPFX##2, s2)                  \
    DOT17(WPFX##3, s3) DOT17(WPFX##4, s4)                                     \
    U0 = RCP(quad_sum(s0)) * 0x1p+40f;                                        \
    U1 = RCP(quad_sum(s1)) * 0x1p+40f;                                        \
    U2 = RCP(quad_sum(s2)) * 0x1p+40f;                                        \
    U3 = RCP(quad_sum(s3)) * 0x1p+40f;                                        \
    U4 = RCP(quad_sum(s4)) * 0x1p+40f;                                        \
    if (cq == 0) DST[wa0] = U0;                                               \
    if (cq == 1) DST[wa1] = U1;                                               \
    if (cq == 2) DST[wa2] = U2;                                               \
    if (cq == 3) DST[wa3] = U3;                                               \
    if (p4 && cq == 0) DST[wa4] = U4; }

#define CT1(w, g) ((w) > 0.0f ? (w) * ((WBIAS - L2(w)) * (1.0f / KGF)) * (g) : 0.0f)
#define CDOT17(PFX, RES)                                                      \
  { float c =  CT1(PFX##_0.x, V0.x) + CT1(PFX##_0.y, V0.y);                   \
    c += CT1(PFX##_1.x, V1.x) + CT1(PFX##_1.y, V1.y);                         \
    c += CT1(PFX##_2.x, V2.x) + CT1(PFX##_2.y, V2.y);                         \
    c += CT1(PFX##_3.x, V3.x) + CT1(PFX##_3.y, V3.y);                         \
    c += CT1(PFX##_4.x, V4.x) + CT1(PFX##_4.y, V4.y);                         \
    c += CT1(PFX##_5.x, V5.x) + CT1(PFX##_5.y, V5.y);                         \
    c += CT1(PFX##_6.x, V6.x) + CT1(PFX##_6.y, V6.y);                         \
    c += CT1(PFX##_7.x, V7.x) + CT1(PFX##_7.y, V7.y);                         \
    c += CT1(PFX##_s, VS);                                                    \
    RES = c; }

__device__ void sink_wave(const float* __restrict__ pred,
                          const float* __restrict__ targ,
                          float* __restrict__ ws, int b) {
  __shared__ float ush[80], vsh[80];
  const int lane = threadIdx.x;        // 0..63 (wave 0 only)
  const int rs = lane >> 2, cq = lane & 3;
  const int c0 = cq * 17;              // logical column base
  const int rb = cq * 20;              // padded LDS read base (80B-aligned)
  const bool p4 = (rs < 4);
  const int r4 = p4 ? 64 + rs : rs;    // clamped; unused when rs>=4

  const float2* pc = (const float2*)(pred + b * NKP * 2);
  const float2* tc = (const float2*)(targ + b * NKP * 2);

  const float2 X0 = pc[rs], X1 = pc[rs + 16], X2 = pc[rs + 32], X3 = pc[rs + 48], X4 = pc[r4];
  const float2 Y0 = tc[rs], Y1 = tc[rs + 16], Y2 = tc[rs + 32], Y3 = tc[rs + 48], Y4 = tc[r4];

  DECLW_F(0, X0) DECLW_F(1, X1) DECLW_F(2, X2) DECLW_F(3, X3) DECLW_F(4, X4)
  DECLW_G(0, Y0) DECLW_G(1, Y1) DECLW_G(2, Y2) DECLW_G(3, Y3) DECLW_G(4, Y4)

  // padded write addresses for owned rows
#define WA(r) (20 * ((r) / 17) + ((r) % 17))
  const int wa0 = WA(rs), wa1 = WA(rs + 16), wa2 = WA(rs + 32),
            wa3 = WA(rs + 48), wa4 = WA(r4);

  vsh[lane] = 1.0f;                    // v0 = 1
  if (lane < 16) vsh[64 + lane] = 1.0f;

  float u0, u1, u2, u3, u4;
  float d0, d1, d2, d3, d4;            // discarded v register outputs
#pragma unroll 1
  for (int it = 0; it < SK_ITERS; ++it) {
    HALF(vsh, ush, wf, u0, u1, u2, u3, u4)   // u = 2^40 / (W v)
    HALF(ush, vsh, wg, d0, d1, d2, d3, d4)   // v = 2^40 / (W^T u)
  }
  (void)d0; (void)d1; (void)d2; (void)d3; (void)d4;

  // cost_b = 2^-40/N * sum_i u_i * sum_j (Wf_ij C_ij) v_j ; C from log2(Wf)
  float local = 0.0f;
  {
    LOADV(vsh)
    float sc0, sc1, sc2, sc3, sc4;
    CDOT17(wf0, sc0) CDOT17(wf1, sc1) CDOT17(wf2, sc2)
    CDOT17(wf3, sc3) CDOT17(wf4, sc4)
    sc0 = quad_sum(sc0); sc1 = quad_sum(sc1); sc2 = quad_sum(sc2);
    sc3 = quad_sum(sc3); sc4 = quad_sum(sc4);
    if (cq == 0) {
      local = u0 * sc0 + u1 * sc1 + u2 * sc2 + u3 * sc3;
      if (p4) local = fmaf(u4, sc4, local);
    }
  }
  local += __shfl_down(local, 32);
  local += __shfl_down(local, 16);
  local += __shfl_down(local, 8);
  local += __shfl_down(local, 4);
  if (lane == 0) ws[WS_COST + b] = local * (0x1p-40f / 68.0f);
}

// ---------------------------------------------------------------------------
// BCE: block = one batch x 8-row y-tile x 128-col x-half (unchanged).
// ---------------------------------------------------------------------------
__device__ void bce_part(const float* __restrict__ pred,
                         const float* __restrict__ targ,
                         float* __restrict__ ws, int bidx) {
  __shared__ float ls[4][NKP];
  __shared__ __attribute__((aligned(16))) float gyp8[NKP][8];
  __shared__ __attribute__((aligned(16))) float gyt8[NKP][8];
  __shared__ float pxp_s[NKP], pxt_s[NKP];
  __shared__ float sS[2];
  __shared__ float bred[3];

  const int b = bidx >> 6;
  const int t6 = bidx & 63;
  const int y0 = (t6 >> 1) * 8;
  const int xbase = (t6 & 1) * 128;
  const int tid = threadIdx.x;

  for (int idx = tid; idx < 272; idx += 192) {
    const int n = idx >> 2, slot = idx & 3;          // 0 px,1 py,2 tx,3 ty
    const float* src = (slot < 2) ? pred : targ;
    const float c = src[(b * NKP + n) * 2 + (slot & 1)] * 255.0f;
    int x0 = (int)c - 19;
    x0 = max(0, min(216, x0));
    float g0 = (float)x0 - c, g1 = g0 + 1.0f, g2 = g0 + 2.0f, g3 = g0 + 3.0f;
    float s0 = 0, s1 = 0, s2 = 0, s3 = 0;
#pragma unroll 2
    for (int v = 0; v < 10; ++v) {
      s0 += E2(g0 * g0 * C2X);
      s1 += E2(g1 * g1 * C2X);
      s2 += E2(g2 * g2 * C2X);
      s3 += E2(g3 * g3 * C2X);
      g0 += 4.0f; g1 += 4.0f; g2 += 4.0f; g3 += 4.0f;
    }
    ls[slot][n] = (s0 + s1) + (s2 + s3);
  }
  for (int idx = tid; idx < NKP * 2; idx += 192) {
    const int n = idx >> 1, tsel = idx & 1;
    const float* c = tsel ? targ : pred;
    float v = c[(b * NKP + n) * 2] * 255.0f;
    (tsel ? pxt_s : pxp_s)[n] = v;
  }
  for (int idx = tid; idx < NKP * 16; idx += 192) {
    const int t2 = idx & 1, rr = (idx >> 1) & 7, n = idx >> 4;
    const float* c = t2 ? targ : pred;
    float py = c[(b * NKP + n) * 2 + 1] * 255.0f;
    float dy = (float)(y0 + rr) - py;
    (t2 ? gyt8 : gyp8)[n][rr] = E2(dy * dy * C2X);
  }
  __syncthreads();

  if (tid < 64) {
    float sp = ls[0][tid] * ls[1][tid];
    float st = ls[2][tid] * ls[3][tid];
    if (tid < 4) {
      sp += ls[0][64 + tid] * ls[1][64 + tid];
      st += ls[2][64 + tid] * ls[3][64 + tid];
    }
    for (int o = 32; o; o >>= 1) { sp += __shfl_down(sp, o); st += __shfl_down(st, o); }
    if (tid == 0) { sS[0] = sp; sS[1] = st; }
  }
  __syncthreads();

  float accp[8] = {0, 0, 0, 0, 0, 0, 0, 0};
  float acct[8] = {0, 0, 0, 0, 0, 0, 0, 0};
  if (tid < 128) {
    const float fx = (float)(xbase + tid);
    for (int n = 0; n < NKP; ++n) {
      float dxp = fx - pxp_s[n];
      float gxp = E2(dxp * dxp * C2X);
      float dxt = fx - pxt_s[n];
      float gxt = E2(dxt * dxt * C2X);
      const float4 gp0 = *(const float4*)&gyp8[n][0];
      const float4 gp1 = *(const float4*)&gyp8[n][4];
      const float4 gt0 = *(const float4*)&gyt8[n][0];
      const float4 gt1 = *(const float4*)&gyt8[n][4];
      accp[0] = fmaf(gp0.x, gxp, accp[0]);
      accp[1] = fmaf(gp0.y, gxp, accp[1]);
      accp[2] = fmaf(gp0.z, gxp, accp[2]);
      accp[3] = fmaf(gp0.w, gxp, accp[3]);
      accp[4] = fmaf(gp1.x, gxp, accp[4]);
      accp[5] = fmaf(gp1.y, gxp, accp[5]);
      accp[6] = fmaf(gp1.z, gxp, accp[6]);
      accp[7] = fmaf(gp1.w, gxp, accp[7]);
      acct[0] = fmaf(gt0.x, gxt, acct[0]);
      acct[1] = fmaf(gt0.y, gxt, acct[1]);
      acct[2] = fmaf(gt0.z, gxt, acct[2]);
      acct[3] = fmaf(gt0.w, gxt, acct[3]);
      acct[4] = fmaf(gt1.x, gxt, acct[4]);
      acct[5] = fmaf(gt1.y, gxt, acct[5]);
      acct[6] = fmaf(gt1.z, gxt, acct[6]);
      acct[7] = fmaf(gt1.w, gxt, acct[7]);
    }
  }

  float local = 0.0f;
  if (tid < 128) {
    const float rsp = 1.0f / (sS[0] + 1e-8f);
    const float rst = 1.0f / sS[1];
#pragma unroll
    for (int rr = 0; rr < 8; ++rr) {
      float p = accp[rr] * rsp;
      float t = acct[rr] * rst;
      float lp = fmaxf(LN2 * L2(p), -100.0f);
      float l1 = fmaxf(LN2 * L2(1.0f - p), -100.0f);
      local += t * lp + (1.0f - t) * l1;
    }
  }
  for (int o = 32; o; o >>= 1) local += __shfl_down(local, o);
  if ((tid & 63) == 0) bred[tid >> 6] = local;
  __syncthreads();
  if (tid == 0)
    ws[WS_BCE0 + bidx] = bred[0] + bred[1] + bred[2];   // plain store
}

// ---------------------------------------------------------------------------
// Fused kernel: blocks 0..15 sinkhorn (wave 0 only), 16..1039 BCE, then a
// last-block-reduces tail (fence + device atomic counter) writes the output.
// ---------------------------------------------------------------------------
__global__ __launch_bounds__(192, 2) void k_main(const float* __restrict__ pred,
                                                 const float* __restrict__ targ,
                                                 float* __restrict__ ws,
                                                 float* __restrict__ out) {
  if (blockIdx.x < 16) {
    if (threadIdx.x < 64) sink_wave(pred, targ, ws, blockIdx.x);
  } else {
    bce_part(pred, targ, ws, blockIdx.x - 16);
  }

  // ---- fused finalization ----
  __shared__ int lastf;
  __syncthreads();
  if (threadIdx.x == 0) {
    __threadfence();                                   // release my partial
    int t = atomicAdd((int*)(ws + WS_CNT), 1);         // device-scope
    lastf = (t == NBLK - 1) ? 1 : 0;
  }
  __syncthreads();
  if (lastf) {
    __threadfence();                                   // acquire all partials
    float vb = 0.0f;
    for (int i = threadIdx.x; i < 1024; i += 192) vb += ws[WS_BCE0 + i];
    float vc = (threadIdx.x < NB) ? ws[WS_COST + threadIdx.x] : 0.0f;
    for (int o = 32; o; o >>= 1) { vb += __shfl_down(vb, o); vc += __shfl_down(vc, o); }
    __shared__ float redb[3], redc[3];
    if ((threadIdx.x & 63) == 0) { redb[threadIdx.x >> 6] = vb; redc[threadIdx.x >> 6] = vc; }
    __syncthreads();
    if (threadIdx.x == 0) {
      float B = redb[0] + redb[1] + redb[2];
      float C = redc[0] + redc[1] + redc[2];
      out[0] = -B * (1000000.0f / 1048576.0f) + C * (2000.0f / 16.0f);
    }
  }
}

extern "C" void kernel_launch(void* const* d_in, const int* in_sizes, int n_in,
                              void* d_out, int out_size, void* d_ws, size_t ws_size,
                              hipStream_t stream) {
  const float* pred = (const float*)d_in[0];
  const float* targ = (const float*)d_in[1];
  float* ws = (float*)d_ws;
  float* out = (float*)d_out;

  hipMemsetAsync((char*)d_ws + WS_CNT * sizeof(float), 0, sizeof(int), stream);
  k_main<<<NBLK, 192, 0, stream>>>(pred, targ, ws, out);
}

// Round 9
// 43.781 us; speedup vs baseline: 1.0991x; 1.0991x over previous
//
#include <hip/hip_runtime.h>
#include <math.h>

#define NKP 68
#define NB 16
#define SK_ITERS 50
#define NBLK (16 + NB * 64)            // 1040 blocks total

#define INVV 0.03125f                  // 1/(2*sigma^2), sigma=4
#define LOG_A (-4.219507705176107f)    // -log(68)
#define L2E 1.4426950408889634f
#define LN2 0.6931471805599453f
#define KGF (100.0f * L2E)             // (1/eps)*log2(e)
#define SW 40.0f                       // power-of-two shift baked into W
#define WBIAS (L2E * LOG_A + SW)
#define C2X (-INVV * 1.4426950408889634f)  // gaussian exponent, base-2

// workspace float offsets
#define WS_COST 0     // [16]   sinkhorn per-batch cost
#define WS_BCE0 16    // [1024] per-block bce partial sums
#define WS_CNT  1056  // [1]    int completion counter (memset per call)

typedef float f32x2 __attribute__((ext_vector_type(2)));

__device__ __forceinline__ float E2(float x) {
#if __has_builtin(__builtin_amdgcn_exp2f)
  return __builtin_amdgcn_exp2f(x);
#else
  return exp2f(x);
#endif
}
__device__ __forceinline__ float L2(float x) {
#if __has_builtin(__builtin_amdgcn_logf)
  return __builtin_amdgcn_logf(x);   // v_log_f32 = log2
#else
  return log2f(x);
#endif
}
__device__ __forceinline__ float RCP(float x) {
#if __has_builtin(__builtin_amdgcn_rcpf)
  return __builtin_amdgcn_rcpf(x);   // v_rcp_f32, ~1 ulp
#else
  return 1.0f / x;
#endif
}
__device__ __forceinline__ f32x2 fma2(f32x2 a, f32x2 b, f32x2 c) {
#if __has_builtin(__builtin_elementwise_fma)
  return __builtin_elementwise_fma(a, b, c);   // -> v_pk_fma_f32
#else
  f32x2 r; r.x = fmaf(a.x, b.x, c.x); r.y = fmaf(a.y, b.y, c.y); return r;
#endif
}
// sum over lane pair (DPP quad_perm xor1) — both lanes get the total
__device__ __forceinline__ float dpp_xor1_add(float s) {
#if __has_builtin(__builtin_amdgcn_mov_dpp)
  int t = __builtin_amdgcn_mov_dpp(__float_as_int(s), 0xB1, 0xF, 0xF, true);
  return s + __int_as_float(t);
#else
  return s + __shfl_xor(s, 1);
#endif
}
// W_ij = 2^40 * exp(-C_ij/eps)/N, computed in base 2
__device__ __forceinline__ float wcomp(float2 a, float2 b) {
  float d0 = a.x - b.x, d1 = a.y - b.y;
  return E2(fmaf(-KGF, d0 * d0 + d1 * d1, WBIAS));
}

// ---------------------------------------------------------------------------
// Sinkhorn in SCALING form, round-7 geometry (2 lanes/row, 136 lanes, known
// no-spill) with W as 17 named f32x2 per matrix -> packed v_pk_fma_f32 dot.
// ---------------------------------------------------------------------------
#define DECLW_F                                                                \
  const f32x2 wf0  = {wcomp(xi, tc[j0+ 0]), wcomp(xi, tc[j0+ 1])};             \
  const f32x2 wf1  = {wcomp(xi, tc[j0+ 2]), wcomp(xi, tc[j0+ 3])};             \
  const f32x2 wf2  = {wcomp(xi, tc[j0+ 4]), wcomp(xi, tc[j0+ 5])};             \
  const f32x2 wf3  = {wcomp(xi, tc[j0+ 6]), wcomp(xi, tc[j0+ 7])};             \
  const f32x2 wf4  = {wcomp(xi, tc[j0+ 8]), wcomp(xi, tc[j0+ 9])};             \
  const f32x2 wf5  = {wcomp(xi, tc[j0+10]), wcomp(xi, tc[j0+11])};             \
  const f32x2 wf6  = {wcomp(xi, tc[j0+12]), wcomp(xi, tc[j0+13])};             \
  const f32x2 wf7  = {wcomp(xi, tc[j0+14]), wcomp(xi, tc[j0+15])};             \
  const f32x2 wf8  = {wcomp(xi, tc[j0+16]), wcomp(xi, tc[j0+17])};             \
  const f32x2 wf9  = {wcomp(xi, tc[j0+18]), wcomp(xi, tc[j0+19])};             \
  const f32x2 wf10 = {wcomp(xi, tc[j0+20]), wcomp(xi, tc[j0+21])};             \
  const f32x2 wf11 = {wcomp(xi, tc[j0+22]), wcomp(xi, tc[j0+23])};             \
  const f32x2 wf12 = {wcomp(xi, tc[j0+24]), wcomp(xi, tc[j0+25])};             \
  const f32x2 wf13 = {wcomp(xi, tc[j0+26]), wcomp(xi, tc[j0+27])};             \
  const f32x2 wf14 = {wcomp(xi, tc[j0+28]), wcomp(xi, tc[j0+29])};             \
  const f32x2 wf15 = {wcomp(xi, tc[j0+30]), wcomp(xi, tc[j0+31])};             \
  const f32x2 wf16 = {wcomp(xi, tc[j0+32]), wcomp(xi, tc[j0+33])};

#define DECLW_G                                                                \
  const f32x2 wg0  = {wcomp(pc[j0+ 0], yj), wcomp(pc[j0+ 1], yj)};             \
  const f32x2 wg1  = {wcomp(pc[j0+ 2], yj), wcomp(pc[j0+ 3], yj)};             \
  const f32x2 wg2  = {wcomp(pc[j0+ 4], yj), wcomp(pc[j0+ 5], yj)};             \
  const f32x2 wg3  = {wcomp(pc[j0+ 6], yj), wcomp(pc[j0+ 7], yj)};             \
  const f32x2 wg4  = {wcomp(pc[j0+ 8], yj), wcomp(pc[j0+ 9], yj)};             \
  const f32x2 wg5  = {wcomp(pc[j0+10], yj), wcomp(pc[j0+11], yj)};             \
  const f32x2 wg6  = {wcomp(pc[j0+12], yj), wcomp(pc[j0+13], yj)};             \
  const f32x2 wg7  = {wcomp(pc[j0+14], yj), wcomp(pc[j0+15], yj)};             \
  const f32x2 wg8  = {wcomp(pc[j0+16], yj), wcomp(pc[j0+17], yj)};             \
  const f32x2 wg9  = {wcomp(pc[j0+18], yj), wcomp(pc[j0+19], yj)};             \
  const f32x2 wg10 = {wcomp(pc[j0+20], yj), wcomp(pc[j0+21], yj)};             \
  const f32x2 wg11 = {wcomp(pc[j0+22], yj), wcomp(pc[j0+23], yj)};             \
  const f32x2 wg12 = {wcomp(pc[j0+24], yj), wcomp(pc[j0+25], yj)};             \
  const f32x2 wg13 = {wcomp(pc[j0+26], yj), wcomp(pc[j0+27], yj)};             \
  const f32x2 wg14 = {wcomp(pc[j0+28], yj), wcomp(pc[j0+29], yj)};             \
  const f32x2 wg15 = {wcomp(pc[j0+30], yj), wcomp(pc[j0+31], yj)};             \
  const f32x2 wg16 = {wcomp(pc[j0+32], yj), wcomp(pc[j0+33], yj)};

#define LOADV(SRC)                                                             \
    const f32x2* vv = (const f32x2*)&SRC[rb];                                  \
    const f32x2 V0 = vv[0],  V1 = vv[1],  V2 = vv[2],  V3 = vv[3];             \
    const f32x2 V4 = vv[4],  V5 = vv[5],  V6 = vv[6],  V7 = vv[7];             \
    const f32x2 V8 = vv[8],  V9 = vv[9],  V10 = vv[10], V11 = vv[11];          \
    const f32x2 V12 = vv[12], V13 = vv[13], V14 = vv[14], V15 = vv[15];        \
    const f32x2 V16 = vv[16];

// 34-elem dot, two packed-FMA chains (depth 9/8)
#define SINK_HALF(SRC, DST, WP, RESULT)                                        \
  {                                                                            \
    LOADV(SRC)                                                                 \
    f32x2 A = WP##0 * V0;                                                      \
    A = fma2(WP##2,  V2,  A); A = fma2(WP##4,  V4,  A);                        \
    A = fma2(WP##6,  V6,  A); A = fma2(WP##8,  V8,  A);                        \
    A = fma2(WP##10, V10, A); A = fma2(WP##12, V12, A);                        \
    A = fma2(WP##14, V14, A); A = fma2(WP##16, V16, A);                        \
    f32x2 B = WP##1 * V1;                                                      \
    B = fma2(WP##3,  V3,  B); B = fma2(WP##5,  V5,  B);                        \
    B = fma2(WP##7,  V7,  B); B = fma2(WP##9,  V9,  B);                        \
    B = fma2(WP##11, V11, B); B = fma2(WP##13, V13, B);                        \
    B = fma2(WP##15, V15, B);                                                  \
    float s = (A.x + A.y) + (B.x + B.y);                                       \
    s = dpp_xor1_add(s);                                                       \
    RESULT = RCP(s) * 0x1p+40f;                                                \
    if (act && q == 0) DST[wofs] = RESULT;                                     \
  }

#define CT1(w, g) ((w) > 0.0f ? (w) * ((WBIAS - L2(w)) * (1.0f / KGF)) * (g) : 0.0f)
#define CPAIR(W, V) { c0 += CT1(W.x, V.x); c1 += CT1(W.y, V.y); }

__device__ void sink_part(const float* __restrict__ pred,
                          const float* __restrict__ targ,
                          float* __restrict__ ws, int b) {
  __shared__ float ush[80], vsh[80], wred[3];
  const int tid = threadIdx.x;
  const bool act = tid < 136;
  const int r = act ? (tid >> 1) : 0;
  const int q = tid & 1;
  const int rb = q * 40;               // LDS read base (16B aligned, groups of 40)
  const int j0 = act ? q * 34 : 0;

  const float2* pc = (const float2*)(pred + b * NKP * 2);
  const float2* tc = (const float2*)(targ + b * NKP * 2);
  const float2 xi = pc[r];   // pred point, f-row r
  const float2 yj = tc[r];   // targ point, g-row r

  DECLW_F
  DECLW_G

  const int wofs = (r < 34) ? r : r + 6;   // padded write offset
  if (tid < 80) vsh[tid] = 1.0f;           // v0 = exp(g0/eps) = 1
  __syncthreads();

  float u = 0.0f;
#pragma unroll 1
  for (int it = 0; it < SK_ITERS; ++it) {
    float vdummy;
    SINK_HALF(vsh, ush, wf, u)       // f-half: u = 2^40 / (W v)
    __syncthreads();
    SINK_HALF(ush, vsh, wg, vdummy)  // g-half: v = 2^40 / (W^T u)
    (void)vdummy;
    __syncthreads();
  }

  // cost_b = 2^-40/N * sum_i u_i * sum_j (Wf_ij C_ij) v_j ; C from log2(Wf),
  // underflowed W (==0) contributes exactly 0.
  float local = 0.0f;
  {
    LOADV(vsh)
    float c0 = 0, c1 = 0;
    CPAIR(wf0,  V0)  CPAIR(wf1,  V1)  CPAIR(wf2,  V2)  CPAIR(wf3,  V3)
    CPAIR(wf4,  V4)  CPAIR(wf5,  V5)  CPAIR(wf6,  V6)  CPAIR(wf7,  V7)
    CPAIR(wf8,  V8)  CPAIR(wf9,  V9)  CPAIR(wf10, V10) CPAIR(wf11, V11)
    CPAIR(wf12, V12) CPAIR(wf13, V13) CPAIR(wf14, V14) CPAIR(wf15, V15)
    CPAIR(wf16, V16)
    float sc = c0 + c1;
    sc = dpp_xor1_add(sc);
    if (act && q == 0) local = sc * u;
  }
  for (int o = 32; o; o >>= 1) local += __shfl_down(local, o);
  if ((tid & 63) == 0) wred[tid >> 6] = local;
  __syncthreads();
  if (tid == 0)
    ws[WS_COST + b] = (wred[0] + wred[1] + wred[2]) * (0x1p-40f / 68.0f);
}

// ---------------------------------------------------------------------------
// BCE: block = one batch x 8-row y-tile x 128-col x-half (round-7, unchanged).
// ---------------------------------------------------------------------------
__device__ void bce_part(const float* __restrict__ pred,
                         const float* __restrict__ targ,
                         float* __restrict__ ws, int bidx) {
  __shared__ float ls[4][NKP];
  __shared__ __attribute__((aligned(16))) float gyp8[NKP][8];
  __shared__ __attribute__((aligned(16))) float gyt8[NKP][8];
  __shared__ float pxp_s[NKP], pxt_s[NKP];
  __shared__ float sS[2];
  __shared__ float bred[3];

  const int b = bidx >> 6;
  const int t6 = bidx & 63;
  const int y0 = (t6 >> 1) * 8;
  const int xbase = (t6 & 1) * 128;
  const int tid = threadIdx.x;

  for (int idx = tid; idx < 272; idx += 192) {
    const int n = idx >> 2, slot = idx & 3;          // 0 px,1 py,2 tx,3 ty
    const float* src = (slot < 2) ? pred : targ;
    const float c = src[(b * NKP + n) * 2 + (slot & 1)] * 255.0f;
    int x0 = (int)c - 19;
    x0 = max(0, min(216, x0));
    float g0 = (float)x0 - c, g1 = g0 + 1.0f, g2 = g0 + 2.0f, g3 = g0 + 3.0f;
    float s0 = 0, s1 = 0, s2 = 0, s3 = 0;
#pragma unroll 2
    for (int v = 0; v < 10; ++v) {
      s0 += E2(g0 * g0 * C2X);
      s1 += E2(g1 * g1 * C2X);
      s2 += E2(g2 * g2 * C2X);
      s3 += E2(g3 * g3 * C2X);
      g0 += 4.0f; g1 += 4.0f; g2 += 4.0f; g3 += 4.0f;
    }
    ls[slot][n] = (s0 + s1) + (s2 + s3);
  }
  for (int idx = tid; idx < NKP * 2; idx += 192) {
    const int n = idx >> 1, tsel = idx & 1;
    const float* c = tsel ? targ : pred;
    float v = c[(b * NKP + n) * 2] * 255.0f;
    (tsel ? pxt_s : pxp_s)[n] = v;
  }
  for (int idx = tid; idx < NKP * 16; idx += 192) {
    const int t2 = idx & 1, rr = (idx >> 1) & 7, n = idx >> 4;
    const float* c = t2 ? targ : pred;
    float py = c[(b * NKP + n) * 2 + 1] * 255.0f;
    float dy = (float)(y0 + rr) - py;
    (t2 ? gyt8 : gyp8)[n][rr] = E2(dy * dy * C2X);
  }
  __syncthreads();

  if (tid < 64) {
    float sp = ls[0][tid] * ls[1][tid];
    float st = ls[2][tid] * ls[3][tid];
    if (tid < 4) {
      sp += ls[0][64 + tid] * ls[1][64 + tid];
      st += ls[2][64 + tid] * ls[3][64 + tid];
    }
    for (int o = 32; o; o >>= 1) { sp += __shfl_down(sp, o); st += __shfl_down(st, o); }
    if (tid == 0) { sS[0] = sp; sS[1] = st; }
  }
  __syncthreads();

  float accp[8] = {0, 0, 0, 0, 0, 0, 0, 0};
  float acct[8] = {0, 0, 0, 0, 0, 0, 0, 0};
  if (tid < 128) {
    const float fx = (float)(xbase + tid);
    for (int n = 0; n < NKP; ++n) {
      float dxp = fx - pxp_s[n];
      float gxp = E2(dxp * dxp * C2X);
      float dxt = fx - pxt_s[n];
      float gxt = E2(dxt * dxt * C2X);
      const float4 gp0 = *(const float4*)&gyp8[n][0];
      const float4 gp1 = *(const float4*)&gyp8[n][4];
      const float4 gt0 = *(const float4*)&gyt8[n][0];
      const float4 gt1 = *(const float4*)&gyt8[n][4];
      accp[0] = fmaf(gp0.x, gxp, accp[0]);
      accp[1] = fmaf(gp0.y, gxp, accp[1]);
      accp[2] = fmaf(gp0.z, gxp, accp[2]);
      accp[3] = fmaf(gp0.w, gxp, accp[3]);
      accp[4] = fmaf(gp1.x, gxp, accp[4]);
      accp[5] = fmaf(gp1.y, gxp, accp[5]);
      accp[6] = fmaf(gp1.z, gxp, accp[6]);
      accp[7] = fmaf(gp1.w, gxp, accp[7]);
      acct[0] = fmaf(gt0.x, gxt, acct[0]);
      acct[1] = fmaf(gt0.y, gxt, acct[1]);
      acct[2] = fmaf(gt0.z, gxt, acct[2]);
      acct[3] = fmaf(gt0.w, gxt, acct[3]);
      acct[4] = fmaf(gt1.x, gxt, acct[4]);
      acct[5] = fmaf(gt1.y, gxt, acct[5]);
      acct[6] = fmaf(gt1.z, gxt, acct[6]);
      acct[7] = fmaf(gt1.w, gxt, acct[7]);
    }
  }

  float local = 0.0f;
  if (tid < 128) {
    const float rsp = 1.0f / (sS[0] + 1e-8f);
    const float rst = 1.0f / sS[1];
#pragma unroll
    for (int rr = 0; rr < 8; ++rr) {
      float p = accp[rr] * rsp;
      float t = acct[rr] * rst;
      float lp = fmaxf(LN2 * L2(p), -100.0f);
      float l1 = fmaxf(LN2 * L2(1.0f - p), -100.0f);
      local += t * lp + (1.0f - t) * l1;
    }
  }
  for (int o = 32; o; o >>= 1) local += __shfl_down(local, o);
  if ((tid & 63) == 0) bred[tid >> 6] = local;
  __syncthreads();
  if (tid == 0)
    ws[WS_BCE0 + bidx] = bred[0] + bred[1] + bred[2];   // plain store
}

// ---------------------------------------------------------------------------
// Fused kernel: blocks 0..15 sinkhorn, 16..1039 BCE, then last-block tail
// (fence + device atomic counter) reduces all partials and writes the output.
// ---------------------------------------------------------------------------
__global__ __launch_bounds__(192, 3) void k_main(const float* __restrict__ pred,
                                                 const float* __restrict__ targ,
                                                 float* __restrict__ ws,
                                                 float* __restrict__ out) {
  if (blockIdx.x < 16)
    sink_part(pred, targ, ws, blockIdx.x);
  else
    bce_part(pred, targ, ws, blockIdx.x - 16);

  // ---- fused finalization ----
  __shared__ int lastf;
  __syncthreads();
  if (threadIdx.x == 0) {
    __threadfence();                                   // release my partial
    int t = atomicAdd((int*)(ws + WS_CNT), 1);         // device-scope
    lastf = (t == NBLK - 1) ? 1 : 0;
  }
  __syncthreads();
  if (lastf) {
    __threadfence();                                   // acquire all partials
    float vb = 0.0f;
    for (int i = threadIdx.x; i < 1024; i += 192) vb += ws[WS_BCE0 + i];
    float vc = (threadIdx.x < NB) ? ws[WS_COST + threadIdx.x] : 0.0f;
    for (int o = 32; o; o >>= 1) { vb += __shfl_down(vb, o); vc += __shfl_down(vc, o); }
    __shared__ float redb[3], redc[3];
    if ((threadIdx.x & 63) == 0) { redb[threadIdx.x >> 6] = vb; redc[threadIdx.x >> 6] = vc; }
    __syncthreads();
    if (threadIdx.x == 0) {
      float B = redb[0] + redb[1] + redb[2];
      float C = redc[0] + redc[1] + redc[2];
      out[0] = -B * (1000000.0f / 1048576.0f) + C * (2000.0f / 16.0f);
    }
  }
}

extern "C" void kernel_launch(void* const* d_in, const int* in_sizes, int n_in,
                              void* d_out, int out_size, void* d_ws, size_t ws_size,
                              hipStream_t stream) {
  const float* pred = (const float*)d_in[0];
  const float* targ = (const float*)d_in[1];
  float* ws = (float*)d_ws;
  float* out = (float*)d_out;

  hipMemsetAsync((char*)d_ws + WS_CNT * sizeof(float), 0, sizeof(int), stream);
  k_main<<<NBLK, 192, 0, stream>>>(pred, targ, ws, out);
}

// Round 10
// 36.962 us; speedup vs baseline: 1.3019x; 1.1845x over previous
//
#include <hip/hip_runtime.h>
#include <math.h>

#define NKP 68
#define NB 16
#define SK_ITERS 50
#define NBLK (16 + NB * 64)            // 1040 blocks total

#define INVV 0.03125f                  // 1/(2*sigma^2), sigma=4
#define LOG_A (-4.219507705176107f)    // -log(68)
#define L2E 1.4426950408889634f
#define LN2 0.6931471805599453f
#define KGF (100.0f * L2E)             // (1/eps)*log2(e)
#define SW 40.0f                       // power-of-two shift baked into W
#define WBIAS (L2E * LOG_A + SW)
#define C2X (-INVV * 1.4426950408889634f)  // gaussian exponent, base-2

// workspace float offsets
#define WS_COST 0     // [16]   sinkhorn per-batch cost (agent-scope stores)
#define WS_BCE0 16    // [1024] per-block bce partial sums (agent-scope stores)
#define WS_CNT  1056  // [1]    int completion counter (memset per call)

__device__ __forceinline__ float E2(float x) {
#if __has_builtin(__builtin_amdgcn_exp2f)
  return __builtin_amdgcn_exp2f(x);
#else
  return exp2f(x);
#endif
}
__device__ __forceinline__ float L2(float x) {
#if __has_builtin(__builtin_amdgcn_logf)
  return __builtin_amdgcn_logf(x);   // v_log_f32 = log2
#else
  return log2f(x);
#endif
}
__device__ __forceinline__ float RCP(float x) {
#if __has_builtin(__builtin_amdgcn_rcpf)
  return __builtin_amdgcn_rcpf(x);   // v_rcp_f32, ~1 ulp
#else
  return 1.0f / x;
#endif
}
// sum over lane pair (DPP quad_perm xor1) — both lanes get the total
__device__ __forceinline__ float dpp_xor1_add(float s) {
#if __has_builtin(__builtin_amdgcn_mov_dpp)
  int t = __builtin_amdgcn_mov_dpp(__float_as_int(s), 0xB1, 0xF, 0xF, true);
  return s + __int_as_float(t);
#else
  return s + __shfl_xor(s, 1);
#endif
}
// W_ij = 2^40 * exp(-C_ij/eps)/N, computed in base 2
__device__ __forceinline__ float wcomp(float2 a, float2 b) {
  float d0 = a.x - b.x, d1 = a.y - b.y;
  return E2(fmaf(-KGF, d0 * d0 + d1 * d1, WBIAS));
}
// visibility without fences: store completes at the coherent point (bypasses
// the non-coherent per-XCD L2); no buffer_wbl2 is ever emitted.
__device__ __forceinline__ void agent_store(float* p, float v) {
  __hip_atomic_store(p, v, __ATOMIC_RELAXED, __HIP_MEMORY_SCOPE_AGENT);
}
__device__ __forceinline__ float agent_load(const float* p) {
  return __hip_atomic_load(p, __ATOMIC_RELAXED, __HIP_MEMORY_SCOPE_AGENT);
}

// token-paste helper so member access stays outside the paste
#define WREG(WP, N) WP##N

// ---------------------------------------------------------------------------
// Sinkhorn in SCALING form: u = 2^40 / (W v), v = 2^40 / (W^T u).
// Round-7 structure (known no-spill): W in EXPLICIT named float4 registers,
// 2 lanes per row, 136 active lanes in 3 waves.
// ---------------------------------------------------------------------------
__device__ void sink_part(const float* __restrict__ pred,
                          const float* __restrict__ targ,
                          float* __restrict__ ws, int b) {
  __shared__ float ush[80], vsh[80], wred[3];
  const int tid = threadIdx.x;
  const bool act = tid < 136;
  const int r = act ? (tid >> 1) : 0;
  const int q = tid & 1;
  const int rb = q * 40;               // LDS read base (16B aligned, groups of 40)
  const int j0 = act ? q * 34 : 0;

  __builtin_amdgcn_s_setprio(1);       // favor the serial sinkhorn chain

  const float2* pc = (const float2*)(pred + b * NKP * 2);
  const float2* tc = (const float2*)(targ + b * NKP * 2);
  const float2 xi = pc[r];   // pred point, f-row r
  const float2 yj = tc[r];   // targ point, g-row r

  // Wf row (vs targ points), Wg row (transpose: pred points vs yj)
  const float4 wf0 = make_float4(wcomp(xi, tc[j0+ 0]), wcomp(xi, tc[j0+ 1]), wcomp(xi, tc[j0+ 2]), wcomp(xi, tc[j0+ 3]));
  const float4 wf1 = make_float4(wcomp(xi, tc[j0+ 4]), wcomp(xi, tc[j0+ 5]), wcomp(xi, tc[j0+ 6]), wcomp(xi, tc[j0+ 7]));
  const float4 wf2 = make_float4(wcomp(xi, tc[j0+ 8]), wcomp(xi, tc[j0+ 9]), wcomp(xi, tc[j0+10]), wcomp(xi, tc[j0+11]));
  const float4 wf3 = make_float4(wcomp(xi, tc[j0+12]), wcomp(xi, tc[j0+13]), wcomp(xi, tc[j0+14]), wcomp(xi, tc[j0+15]));
  const float4 wf4 = make_float4(wcomp(xi, tc[j0+16]), wcomp(xi, tc[j0+17]), wcomp(xi, tc[j0+18]), wcomp(xi, tc[j0+19]));
  const float4 wf5 = make_float4(wcomp(xi, tc[j0+20]), wcomp(xi, tc[j0+21]), wcomp(xi, tc[j0+22]), wcomp(xi, tc[j0+23]));
  const float4 wf6 = make_float4(wcomp(xi, tc[j0+24]), wcomp(xi, tc[j0+25]), wcomp(xi, tc[j0+26]), wcomp(xi, tc[j0+27]));
  const float4 wf7 = make_float4(wcomp(xi, tc[j0+28]), wcomp(xi, tc[j0+29]), wcomp(xi, tc[j0+30]), wcomp(xi, tc[j0+31]));
  const float2 wf8 = make_float2(wcomp(xi, tc[j0+32]), wcomp(xi, tc[j0+33]));
  const float4 wg0 = make_float4(wcomp(pc[j0+ 0], yj), wcomp(pc[j0+ 1], yj), wcomp(pc[j0+ 2], yj), wcomp(pc[j0+ 3], yj));
  const float4 wg1 = make_float4(wcomp(pc[j0+ 4], yj), wcomp(pc[j0+ 5], yj), wcomp(pc[j0+ 6], yj), wcomp(pc[j0+ 7], yj));
  const float4 wg2 = make_float4(wcomp(pc[j0+ 8], yj), wcomp(pc[j0+ 9], yj), wcomp(pc[j0+10], yj), wcomp(pc[j0+11], yj));
  const float4 wg3 = make_float4(wcomp(pc[j0+12], yj), wcomp(pc[j0+13], yj), wcomp(pc[j0+14], yj), wcomp(pc[j0+15], yj));
  const float4 wg4 = make_float4(wcomp(pc[j0+16], yj), wcomp(pc[j0+17], yj), wcomp(pc[j0+18], yj), wcomp(pc[j0+19], yj));
  const float4 wg5 = make_float4(wcomp(pc[j0+20], yj), wcomp(pc[j0+21], yj), wcomp(pc[j0+22], yj), wcomp(pc[j0+23], yj));
  const float4 wg6 = make_float4(wcomp(pc[j0+24], yj), wcomp(pc[j0+25], yj), wcomp(pc[j0+26], yj), wcomp(pc[j0+27], yj));
  const float4 wg7 = make_float4(wcomp(pc[j0+28], yj), wcomp(pc[j0+29], yj), wcomp(pc[j0+30], yj), wcomp(pc[j0+31], yj));
  const float2 wg8 = make_float2(wcomp(pc[j0+32], yj), wcomp(pc[j0+33], yj));

  const int wofs = (r < 34) ? r : r + 6;   // padded write offset
  if (tid < 80) vsh[tid] = 1.0f;           // v0 = exp(g0/eps) = 1
  __syncthreads();

#define ACC4(W, G)                                                           \
    s0 = fmaf(W.x, G.x, s0); s1 = fmaf(W.y, G.y, s1);                        \
    s2 = fmaf(W.z, G.z, s2); s3 = fmaf(W.w, G.w, s3);

#define SINK_HALF(SRC, DST, WP, RESULT)                                      \
  {                                                                          \
    const float4* gv = (const float4*)&SRC[rb];                              \
    float4 g0 = gv[0], g1 = gv[1], g2 = gv[2], g3 = gv[3];                   \
    float4 g4 = gv[4], g5 = gv[5], g6 = gv[6], g7 = gv[7];                   \
    float2 g8 = *(const float2*)&SRC[rb + 32];                               \
    float s0 = 0, s1 = 0, s2 = 0, s3 = 0;                                    \
    ACC4(WREG(WP,0), g0) ACC4(WREG(WP,1), g1)                                \
    ACC4(WREG(WP,2), g2) ACC4(WREG(WP,3), g3)                                \
    ACC4(WREG(WP,4), g4) ACC4(WREG(WP,5), g5)                                \
    ACC4(WREG(WP,6), g6) ACC4(WREG(WP,7), g7)                                \
    s0 = fmaf(WREG(WP,8).x, g8.x, s0);                                       \
    s1 = fmaf(WREG(WP,8).y, g8.y, s1);                                       \
    float s = (s0 + s1) + (s2 + s3);                                         \
    s = dpp_xor1_add(s);                                                     \
    RESULT = RCP(s) * 0x1p+40f;                                              \
    if (act && q == 0) DST[wofs] = RESULT;                                   \
  }

  float u = 0.0f;
#pragma unroll 1
  for (int it = 0; it < SK_ITERS; ++it) {
    float vdummy;
    SINK_HALF(vsh, ush, wf, u)       // f-half: u = 2^40 / (W v)
    __syncthreads();
    SINK_HALF(ush, vsh, wg, vdummy)  // g-half: v = 2^40 / (W^T u)
    (void)vdummy;
    __syncthreads();
  }

  // cost_b = 2^-40/N * sum_i u_i * sum_j (Wf_ij C_ij) v_j ; C from log2(Wf),
  // underflowed W (==0) contributes exactly 0.
#define CT(w, g) ((w) > 0.0f ? (w) * ((WBIAS - L2(w)) * (1.0f / KGF)) * (g) : 0.0f)
#define CACC4(W, G)                                                          \
    c0 += CT(W.x, G.x); c1 += CT(W.y, G.y);                                  \
    c2 += CT(W.z, G.z); c3 += CT(W.w, G.w);

  float local = 0.0f;
  {
    const float4* gv = (const float4*)&vsh[rb];
    float4 g0 = gv[0], g1 = gv[1], g2 = gv[2], g3 = gv[3];
    float4 g4 = gv[4], g5 = gv[5], g6 = gv[6], g7 = gv[7];
    float2 g8 = *(const float2*)&vsh[rb + 32];
    float c0 = 0, c1 = 0, c2 = 0, c3 = 0;
    CACC4(wf0, g0) CACC4(wf1, g1) CACC4(wf2, g2) CACC4(wf3, g3)
    CACC4(wf4, g4) CACC4(wf5, g5) CACC4(wf6, g6) CACC4(wf7, g7)
    c0 += CT(wf8.x, g8.x); c1 += CT(wf8.y, g8.y);
    float sc = (c0 + c1) + (c2 + c3);
    sc = dpp_xor1_add(sc);
    if (act && q == 0) local = sc * u;
  }
  for (int o = 32; o; o >>= 1) local += __shfl_down(local, o);
  if ((tid & 63) == 0) wred[tid >> 6] = local;
  __syncthreads();
  if (tid == 0)
    agent_store(&ws[WS_COST + b],
                (wred[0] + wred[1] + wred[2]) * (0x1p-40f / 68.0f));
  __builtin_amdgcn_s_setprio(0);
}

// ---------------------------------------------------------------------------
// BCE: block = one batch x 8-row y-tile x 128-col x-half (round-7, unchanged).
// ---------------------------------------------------------------------------
__device__ void bce_part(const float* __restrict__ pred,
                         const float* __restrict__ targ,
                         float* __restrict__ ws, int bidx) {
  __shared__ float ls[4][NKP];
  __shared__ __attribute__((aligned(16))) float gyp8[NKP][8];
  __shared__ __attribute__((aligned(16))) float gyt8[NKP][8];
  __shared__ float pxp_s[NKP], pxt_s[NKP];
  __shared__ float sS[2];
  __shared__ float bred[3];

  const int b = bidx >> 6;
  const int t6 = bidx & 63;
  const int y0 = (t6 >> 1) * 8;
  const int xbase = (t6 & 1) * 128;
  const int tid = threadIdx.x;

  for (int idx = tid; idx < 272; idx += 192) {
    const int n = idx >> 2, slot = idx & 3;          // 0 px,1 py,2 tx,3 ty
    const float* src = (slot < 2) ? pred : targ;
    const float c = src[(b * NKP + n) * 2 + (slot & 1)] * 255.0f;
    int x0 = (int)c - 19;
    x0 = max(0, min(216, x0));
    float g0 = (float)x0 - c, g1 = g0 + 1.0f, g2 = g0 + 2.0f, g3 = g0 + 3.0f;
    float s0 = 0, s1 = 0, s2 = 0, s3 = 0;
#pragma unroll 2
    for (int v = 0; v < 10; ++v) {
      s0 += E2(g0 * g0 * C2X);
      s1 += E2(g1 * g1 * C2X);
      s2 += E2(g2 * g2 * C2X);
      s3 += E2(g3 * g3 * C2X);
      g0 += 4.0f; g1 += 4.0f; g2 += 4.0f; g3 += 4.0f;
    }
    ls[slot][n] = (s0 + s1) + (s2 + s3);
  }
  for (int idx = tid; idx < NKP * 2; idx += 192) {
    const int n = idx >> 1, tsel = idx & 1;
    const float* c = tsel ? targ : pred;
    float v = c[(b * NKP + n) * 2] * 255.0f;
    (tsel ? pxt_s : pxp_s)[n] = v;
  }
  for (int idx = tid; idx < NKP * 16; idx += 192) {
    const int t2 = idx & 1, rr = (idx >> 1) & 7, n = idx >> 4;
    const float* c = t2 ? targ : pred;
    float py = c[(b * NKP + n) * 2 + 1] * 255.0f;
    float dy = (float)(y0 + rr) - py;
    (t2 ? gyt8 : gyp8)[n][rr] = E2(dy * dy * C2X);
  }
  __syncthreads();

  if (tid < 64) {
    float sp = ls[0][tid] * ls[1][tid];
    float st = ls[2][tid] * ls[3][tid];
    if (tid < 4) {
      sp += ls[0][64 + tid] * ls[1][64 + tid];
      st += ls[2][64 + tid] * ls[3][64 + tid];
    }
    for (int o = 32; o; o >>= 1) { sp += __shfl_down(sp, o); st += __shfl_down(st, o); }
    if (tid == 0) { sS[0] = sp; sS[1] = st; }
  }
  __syncthreads();

  float accp[8] = {0, 0, 0, 0, 0, 0, 0, 0};
  float acct[8] = {0, 0, 0, 0, 0, 0, 0, 0};
  if (tid < 128) {
    const float fx = (float)(xbase + tid);
    for (int n = 0; n < NKP; ++n) {
      float dxp = fx - pxp_s[n];
      float gxp = E2(dxp * dxp * C2X);
      float dxt = fx - pxt_s[n];
      float gxt = E2(dxt * dxt * C2X);
      const float4 gp0 = *(const float4*)&gyp8[n][0];
      const float4 gp1 = *(const float4*)&gyp8[n][4];
      const float4 gt0 = *(const float4*)&gyt8[n][0];
      const float4 gt1 = *(const float4*)&gyt8[n][4];
      accp[0] = fmaf(gp0.x, gxp, accp[0]);
      accp[1] = fmaf(gp0.y, gxp, accp[1]);
      accp[2] = fmaf(gp0.z, gxp, accp[2]);
      accp[3] = fmaf(gp0.w, gxp, accp[3]);
      accp[4] = fmaf(gp1.x, gxp, accp[4]);
      accp[5] = fmaf(gp1.y, gxp, accp[5]);
      accp[6] = fmaf(gp1.z, gxp, accp[6]);
      accp[7] = fmaf(gp1.w, gxp, accp[7]);
      acct[0] = fmaf(gt0.x, gxt, acct[0]);
      acct[1] = fmaf(gt0.y, gxt, acct[1]);
      acct[2] = fmaf(gt0.z, gxt, acct[2]);
      acct[3] = fmaf(gt0.w, gxt, acct[3]);
      acct[4] = fmaf(gt1.x, gxt, acct[4]);
      acct[5] = fmaf(gt1.y, gxt, acct[5]);
      acct[6] = fmaf(gt1.z, gxt, acct[6]);
      acct[7] = fmaf(gt1.w, gxt, acct[7]);
    }
  }

  float local = 0.0f;
  if (tid < 128) {
    const float rsp = 1.0f / (sS[0] + 1e-8f);
    const float rst = 1.0f / sS[1];
#pragma unroll
    for (int rr = 0; rr < 8; ++rr) {
      float p = accp[rr] * rsp;
      float t = acct[rr] * rst;
      float lp = fmaxf(LN2 * L2(p), -100.0f);
      float l1 = fmaxf(LN2 * L2(1.0f - p), -100.0f);
      local += t * lp + (1.0f - t) * l1;
    }
  }
  for (int o = 32; o; o >>= 1) local += __shfl_down(local, o);
  if ((tid & 63) == 0) bred[tid >> 6] = local;
  __syncthreads();
  if (tid == 0)
    agent_store(&ws[WS_BCE0 + bidx], bred[0] + bred[1] + bred[2]);
}

// ---------------------------------------------------------------------------
// Fused kernel: blocks 0..15 sinkhorn, 16..1039 BCE; fence-FREE finalization:
// agent-scope partial stores (complete at the coherent point, no wbl2), a
// vmcnt(0) in the storing lane, then an int atomic counter; the 1040th block
// reduces all partials via agent-scope loads and writes the output.
// ---------------------------------------------------------------------------
__global__ __launch_bounds__(192, 3) void k_main(const float* __restrict__ pred,
                                                 const float* __restrict__ targ,
                                                 float* __restrict__ ws,
                                                 float* __restrict__ out) {
  if (blockIdx.x < 16)
    sink_part(pred, targ, ws, blockIdx.x);
  else
    bce_part(pred, targ, ws, blockIdx.x - 16);

  __shared__ int lastf;
  __syncthreads();
  if (threadIdx.x == 0) {
    asm volatile("s_waitcnt vmcnt(0)" ::: "memory");   // my partial is at LLC
    int t = __hip_atomic_fetch_add((int*)(ws + WS_CNT), 1,
                                   __ATOMIC_RELAXED, __HIP_MEMORY_SCOPE_AGENT);
    lastf = (t == NBLK - 1) ? 1 : 0;
  }
  __syncthreads();
  if (lastf) {
    float vb = 0.0f;
    for (int i = threadIdx.x; i < 1024; i += 192) vb += agent_load(&ws[WS_BCE0 + i]);
    float vc = (threadIdx.x < NB) ? agent_load(&ws[WS_COST + threadIdx.x]) : 0.0f;
    for (int o = 32; o; o >>= 1) { vb += __shfl_down(vb, o); vc += __shfl_down(vc, o); }
    __shared__ float redb[3], redc[3];
    if ((threadIdx.x & 63) == 0) { redb[threadIdx.x >> 6] = vb; redc[threadIdx.x >> 6] = vc; }
    __syncthreads();
    if (threadIdx.x == 0) {
      float B = redb[0] + redb[1] + redb[2];
      float C = redc[0] + redc[1] + redc[2];
      out[0] = -B * (1000000.0f / 1048576.0f) + C * (2000.0f / 16.0f);
    }
  }
}

extern "C" void kernel_launch(void* const* d_in, const int* in_sizes, int n_in,
                              void* d_out, int out_size, void* d_ws, size_t ws_size,
                              hipStream_t stream) {
  const float* pred = (const float*)d_in[0];
  const float* targ = (const float*)d_in[1];
  float* ws = (float*)d_ws;
  float* out = (float*)d_out;

  hipMemsetAsync((char*)d_ws + WS_CNT * sizeof(float), 0, sizeof(int), stream);
  k_main<<<NBLK, 192, 0, stream>>>(pred, targ, ws, out);
}

// Round 11
// 29.217 us; speedup vs baseline: 1.6471x; 1.2651x over previous
//
#include <hip/hip_runtime.h>
#include <math.h>

#define NKP 68
#define NB 16
#define SK_ITERS 50

#define INVV 0.03125f                  // 1/(2*sigma^2), sigma=4
#define LOG_A (-4.219507705176107f)    // -log(68)
#define L2E 1.4426950408889634f
#define LN2 0.6931471805599453f
#define KGF (100.0f * L2E)             // (1/eps)*log2(e)
#define SW 40.0f                       // power-of-two shift baked into W
#define WBIAS (L2E * LOG_A + SW)
#define C2X (-INVV * 1.4426950408889634f)  // gaussian exponent, base-2

// workspace float offsets (all plain stores, no init needed)
#define WS_COST 0     // [16]   sinkhorn per-batch cost
#define WS_BCE0 16    // [1024] per-block bce partial sums

__device__ __forceinline__ float E2(float x) {
#if __has_builtin(__builtin_amdgcn_exp2f)
  return __builtin_amdgcn_exp2f(x);
#else
  return exp2f(x);
#endif
}
__device__ __forceinline__ float L2(float x) {
#if __has_builtin(__builtin_amdgcn_logf)
  return __builtin_amdgcn_logf(x);   // v_log_f32 = log2
#else
  return log2f(x);
#endif
}
__device__ __forceinline__ float RCP(float x) {
#if __has_builtin(__builtin_amdgcn_rcpf)
  return __builtin_amdgcn_rcpf(x);   // v_rcp_f32, ~1 ulp
#else
  return 1.0f / x;
#endif
}
// sum over lane pair (DPP quad_perm xor1) — both lanes get the total
__device__ __forceinline__ float dpp_xor1_add(float s) {
#if __has_builtin(__builtin_amdgcn_mov_dpp)
  int t = __builtin_amdgcn_mov_dpp(__float_as_int(s), 0xB1, 0xF, 0xF, true);
  return s + __int_as_float(t);
#else
  return s + __shfl_xor(s, 1);
#endif
}
// W_ij = 2^40 * exp(-C_ij/eps)/N, computed in base 2
__device__ __forceinline__ float wcomp(float2 a, float2 b) {
  float d0 = a.x - b.x, d1 = a.y - b.y;
  return E2(fmaf(-KGF, d0 * d0 + d1 * d1, WBIAS));
}

// token-paste helper so member access stays outside the paste
// (WP##8.x fails: "8.x" lexes as one pp-number token)
#define WREG(WP, N) WP##N

// ---------------------------------------------------------------------------
// Sinkhorn in SCALING form: u = 2^40 / (W v), v = 2^40 / (W^T u).
// W held in EXPLICIT named float4 registers (no local arrays -> no alloca ->
// no scratch). 2 lanes per row, 136 active lanes in 3 waves.
// s_setprio(1) for the whole body: these 48 waves are the serial critical
// path; during the first ~5 µs they share CUs with ~12 BCE waves/CU (T5
// role-split regime), and priority reclaims VALU issue slots.
// ---------------------------------------------------------------------------
__device__ void sink_part(const float* __restrict__ pred,
                          const float* __restrict__ targ,
                          float* __restrict__ ws, int b) {
  __shared__ float ush[80], vsh[80], wred[3];
  const int tid = threadIdx.x;
  const bool act = tid < 136;
  const int r = act ? (tid >> 1) : 0;
  const int q = tid & 1;
  const int rb = q * 40;               // LDS read base (16B aligned, groups of 40)
  const int j0 = act ? q * 34 : 0;

  __builtin_amdgcn_s_setprio(1);

  const float2* pc = (const float2*)(pred + b * NKP * 2);
  const float2* tc = (const float2*)(targ + b * NKP * 2);
  const float2 xi = pc[r];   // pred point, f-row r
  const float2 yj = tc[r];   // targ point, g-row r

  // Wf row (vs targ points), Wg row (transpose: pred points vs yj)
  const float4 wf0 = make_float4(wcomp(xi, tc[j0+ 0]), wcomp(xi, tc[j0+ 1]), wcomp(xi, tc[j0+ 2]), wcomp(xi, tc[j0+ 3]));
  const float4 wf1 = make_float4(wcomp(xi, tc[j0+ 4]), wcomp(xi, tc[j0+ 5]), wcomp(xi, tc[j0+ 6]), wcomp(xi, tc[j0+ 7]));
  const float4 wf2 = make_float4(wcomp(xi, tc[j0+ 8]), wcomp(xi, tc[j0+ 9]), wcomp(xi, tc[j0+10]), wcomp(xi, tc[j0+11]));
  const float4 wf3 = make_float4(wcomp(xi, tc[j0+12]), wcomp(xi, tc[j0+13]), wcomp(xi, tc[j0+14]), wcomp(xi, tc[j0+15]));
  const float4 wf4 = make_float4(wcomp(xi, tc[j0+16]), wcomp(xi, tc[j0+17]), wcomp(xi, tc[j0+18]), wcomp(xi, tc[j0+19]));
  const float4 wf5 = make_float4(wcomp(xi, tc[j0+20]), wcomp(xi, tc[j0+21]), wcomp(xi, tc[j0+22]), wcomp(xi, tc[j0+23]));
  const float4 wf6 = make_float4(wcomp(xi, tc[j0+24]), wcomp(xi, tc[j0+25]), wcomp(xi, tc[j0+26]), wcomp(xi, tc[j0+27]));
  const float4 wf7 = make_float4(wcomp(xi, tc[j0+28]), wcomp(xi, tc[j0+29]), wcomp(xi, tc[j0+30]), wcomp(xi, tc[j0+31]));
  const float2 wf8 = make_float2(wcomp(xi, tc[j0+32]), wcomp(xi, tc[j0+33]));
  const float4 wg0 = make_float4(wcomp(pc[j0+ 0], yj), wcomp(pc[j0+ 1], yj), wcomp(pc[j0+ 2], yj), wcomp(pc[j0+ 3], yj));
  const float4 wg1 = make_float4(wcomp(pc[j0+ 4], yj), wcomp(pc[j0+ 5], yj), wcomp(pc[j0+ 6], yj), wcomp(pc[j0+ 7], yj));
  const float4 wg2 = make_float4(wcomp(pc[j0+ 8], yj), wcomp(pc[j0+ 9], yj), wcomp(pc[j0+10], yj), wcomp(pc[j0+11], yj));
  const float4 wg3 = make_float4(wcomp(pc[j0+12], yj), wcomp(pc[j0+13], yj), wcomp(pc[j0+14], yj), wcomp(pc[j0+15], yj));
  const float4 wg4 = make_float4(wcomp(pc[j0+16], yj), wcomp(pc[j0+17], yj), wcomp(pc[j0+18], yj), wcomp(pc[j0+19], yj));
  const float4 wg5 = make_float4(wcomp(pc[j0+20], yj), wcomp(pc[j0+21], yj), wcomp(pc[j0+22], yj), wcomp(pc[j0+23], yj));
  const float4 wg6 = make_float4(wcomp(pc[j0+24], yj), wcomp(pc[j0+25], yj), wcomp(pc[j0+26], yj), wcomp(pc[j0+27], yj));
  const float4 wg7 = make_float4(wcomp(pc[j0+28], yj), wcomp(pc[j0+29], yj), wcomp(pc[j0+30], yj), wcomp(pc[j0+31], yj));
  const float2 wg8 = make_float2(wcomp(pc[j0+32], yj), wcomp(pc[j0+33], yj));

  const int wofs = (r < 34) ? r : r + 6;   // padded write offset
  if (tid < 80) vsh[tid] = 1.0f;           // v0 = exp(g0/eps) = 1
  __syncthreads();

#define ACC4(W, G)                                                           \
    s0 = fmaf(W.x, G.x, s0); s1 = fmaf(W.y, G.y, s1);                        \
    s2 = fmaf(W.z, G.z, s2); s3 = fmaf(W.w, G.w, s3);

#define SINK_HALF(SRC, DST, WP, RESULT)                                      \
  {                                                                          \
    const float4* gv = (const float4*)&SRC[rb];                              \
    float4 g0 = gv[0], g1 = gv[1], g2 = gv[2], g3 = gv[3];                   \
    float4 g4 = gv[4], g5 = gv[5], g6 = gv[6], g7 = gv[7];                   \
    float2 g8 = *(const float2*)&SRC[rb + 32];                               \
    float s0 = 0, s1 = 0, s2 = 0, s3 = 0;                                    \
    ACC4(WREG(WP,0), g0) ACC4(WREG(WP,1), g1)                                \
    ACC4(WREG(WP,2), g2) ACC4(WREG(WP,3), g3)                                \
    ACC4(WREG(WP,4), g4) ACC4(WREG(WP,5), g5)                                \
    ACC4(WREG(WP,6), g6) ACC4(WREG(WP,7), g7)                                \
    s0 = fmaf(WREG(WP,8).x, g8.x, s0);                                       \
    s1 = fmaf(WREG(WP,8).y, g8.y, s1);                                       \
    float s = (s0 + s1) + (s2 + s3);                                         \
    s = dpp_xor1_add(s);                                                     \
    RESULT = RCP(s) * 0x1p+40f;                                              \
    if (act && q == 0) DST[wofs] = RESULT;                                   \
  }

  float u = 0.0f;
#pragma unroll 1
  for (int it = 0; it < SK_ITERS; ++it) {
    float vdummy;
    SINK_HALF(vsh, ush, wf, u)       // f-half: u = 2^40 / (W v)
    __syncthreads();
    SINK_HALF(ush, vsh, wg, vdummy)  // g-half: v = 2^40 / (W^T u)
    (void)vdummy;
    __syncthreads();
  }

  // cost_b = 2^-40/N * sum_i u_i * sum_j (Wf_ij C_ij) v_j ; C from log2(Wf),
  // underflowed W (==0) contributes exactly 0.
#define CT(w, g) ((w) > 0.0f ? (w) * ((WBIAS - L2(w)) * (1.0f / KGF)) * (g) : 0.0f)
#define CACC4(W, G)                                                          \
    c0 += CT(W.x, G.x); c1 += CT(W.y, G.y);                                  \
    c2 += CT(W.z, G.z); c3 += CT(W.w, G.w);

  float local = 0.0f;
  {
    const float4* gv = (const float4*)&vsh[rb];
    float4 g0 = gv[0], g1 = gv[1], g2 = gv[2], g3 = gv[3];
    float4 g4 = gv[4], g5 = gv[5], g6 = gv[6], g7 = gv[7];
    float2 g8 = *(const float2*)&vsh[rb + 32];
    float c0 = 0, c1 = 0, c2 = 0, c3 = 0;
    CACC4(wf0, g0) CACC4(wf1, g1) CACC4(wf2, g2) CACC4(wf3, g3)
    CACC4(wf4, g4) CACC4(wf5, g5) CACC4(wf6, g6) CACC4(wf7, g7)
    c0 += CT(wf8.x, g8.x); c1 += CT(wf8.y, g8.y);
    float sc = (c0 + c1) + (c2 + c3);
    sc = dpp_xor1_add(sc);
    if (act && q == 0) local = sc * u;
  }
  for (int o = 32; o; o >>= 1) local += __shfl_down(local, o);
  if ((tid & 63) == 0) wred[tid >> 6] = local;
  __syncthreads();
  if (tid == 0)
    ws[WS_COST + b] = (wred[0] + wred[1] + wred[2]) * (0x1p-40f / 68.0f);
  __builtin_amdgcn_s_setprio(0);
}

// ---------------------------------------------------------------------------
// BCE: block = one batch x 8-row y-tile x 128-col x-half. Windowed (40-sample)
// per-axis gaussian sums for normalization; gy staged in LDS; gx recomputed.
// ---------------------------------------------------------------------------
__device__ void bce_part(const float* __restrict__ pred,
                         const float* __restrict__ targ,
                         float* __restrict__ ws, int bidx) {
  __shared__ float ls[4][NKP];
  __shared__ __attribute__((aligned(16))) float gyp8[NKP][8];
  __shared__ __attribute__((aligned(16))) float gyt8[NKP][8];
  __shared__ float pxp_s[NKP], pxt_s[NKP];
  __shared__ float sS[2];
  __shared__ float bred[3];

  const int b = bidx >> 6;
  const int t6 = bidx & 63;
  const int y0 = (t6 >> 1) * 8;
  const int xbase = (t6 & 1) * 128;
  const int tid = threadIdx.x;

  for (int idx = tid; idx < 272; idx += 192) {
    const int n = idx >> 2, slot = idx & 3;          // 0 px,1 py,2 tx,3 ty
    const float* src = (slot < 2) ? pred : targ;
    const float c = src[(b * NKP + n) * 2 + (slot & 1)] * 255.0f;
    int x0 = (int)c - 19;
    x0 = max(0, min(216, x0));
    float g0 = (float)x0 - c, g1 = g0 + 1.0f, g2 = g0 + 2.0f, g3 = g0 + 3.0f;
    float s0 = 0, s1 = 0, s2 = 0, s3 = 0;
#pragma unroll 2
    for (int v = 0; v < 10; ++v) {
      s0 += E2(g0 * g0 * C2X);
      s1 += E2(g1 * g1 * C2X);
      s2 += E2(g2 * g2 * C2X);
      s3 += E2(g3 * g3 * C2X);
      g0 += 4.0f; g1 += 4.0f; g2 += 4.0f; g3 += 4.0f;
    }
    ls[slot][n] = (s0 + s1) + (s2 + s3);
  }
  for (int idx = tid; idx < NKP * 2; idx += 192) {
    const int n = idx >> 1, tsel = idx & 1;
    const float* c = tsel ? targ : pred;
    float v = c[(b * NKP + n) * 2] * 255.0f;
    (tsel ? pxt_s : pxp_s)[n] = v;
  }
  for (int idx = tid; idx < NKP * 16; idx += 192) {
    const int t2 = idx & 1, rr = (idx >> 1) & 7, n = idx >> 4;
    const float* c = t2 ? targ : pred;
    float py = c[(b * NKP + n) * 2 + 1] * 255.0f;
    float dy = (float)(y0 + rr) - py;
    (t2 ? gyt8 : gyp8)[n][rr] = E2(dy * dy * C2X);
  }
  __syncthreads();

  if (tid < 64) {
    float sp = ls[0][tid] * ls[1][tid];
    float st = ls[2][tid] * ls[3][tid];
    if (tid < 4) {
      sp += ls[0][64 + tid] * ls[1][64 + tid];
      st += ls[2][64 + tid] * ls[3][64 + tid];
    }
    for (int o = 32; o; o >>= 1) { sp += __shfl_down(sp, o); st += __shfl_down(st, o); }
    if (tid == 0) { sS[0] = sp; sS[1] = st; }
  }
  __syncthreads();

  float accp[8] = {0, 0, 0, 0, 0, 0, 0, 0};
  float acct[8] = {0, 0, 0, 0, 0, 0, 0, 0};
  if (tid < 128) {
    const float fx = (float)(xbase + tid);
    for (int n = 0; n < NKP; ++n) {
      float dxp = fx - pxp_s[n];
      float gxp = E2(dxp * dxp * C2X);
      float dxt = fx - pxt_s[n];
      float gxt = E2(dxt * dxt * C2X);
      const float4 gp0 = *(const float4*)&gyp8[n][0];
      const float4 gp1 = *(const float4*)&gyp8[n][4];
      const float4 gt0 = *(const float4*)&gyt8[n][0];
      const float4 gt1 = *(const float4*)&gyt8[n][4];
      accp[0] = fmaf(gp0.x, gxp, accp[0]);
      accp[1] = fmaf(gp0.y, gxp, accp[1]);
      accp[2] = fmaf(gp0.z, gxp, accp[2]);
      accp[3] = fmaf(gp0.w, gxp, accp[3]);
      accp[4] = fmaf(gp1.x, gxp, accp[4]);
      accp[5] = fmaf(gp1.y, gxp, accp[5]);
      accp[6] = fmaf(gp1.z, gxp, accp[6]);
      accp[7] = fmaf(gp1.w, gxp, accp[7]);
      acct[0] = fmaf(gt0.x, gxt, acct[0]);
      acct[1] = fmaf(gt0.y, gxt, acct[1]);
      acct[2] = fmaf(gt0.z, gxt, acct[2]);
      acct[3] = fmaf(gt0.w, gxt, acct[3]);
      acct[4] = fmaf(gt1.x, gxt, acct[4]);
      acct[5] = fmaf(gt1.y, gxt, acct[5]);
      acct[6] = fmaf(gt1.z, gxt, acct[6]);
      acct[7] = fmaf(gt1.w, gxt, acct[7]);
    }
  }

  float local = 0.0f;
  if (tid < 128) {
    const float rsp = 1.0f / (sS[0] + 1e-8f);
    const float rst = 1.0f / sS[1];
#pragma unroll
    for (int rr = 0; rr < 8; ++rr) {
      float p = accp[rr] * rsp;
      float t = acct[rr] * rst;
      float lp = fmaxf(LN2 * L2(p), -100.0f);
      float l1 = fmaxf(LN2 * L2(1.0f - p), -100.0f);
      local += t * lp + (1.0f - t) * l1;
    }
  }
  for (int o = 32; o; o >>= 1) local += __shfl_down(local, o);
  if ((tid & 63) == 0) bred[tid >> 6] = local;
  __syncthreads();
  if (tid == 0)
    ws[WS_BCE0 + bidx] = bred[0] + bred[1] + bred[2];   // plain store
}

// ---------------------------------------------------------------------------
// Fused main kernel: blocks 0..15 sinkhorn, 16..1039 BCE.
// ---------------------------------------------------------------------------
__global__ __launch_bounds__(192, 3) void k_main(const float* __restrict__ pred,
                                                 const float* __restrict__ targ,
                                                 float* __restrict__ ws) {
  if (blockIdx.x < 16)
    sink_part(pred, targ, ws, blockIdx.x);
  else
    bce_part(pred, targ, ws, blockIdx.x - 16);
}

// ---------------------------------------------------------------------------
// Final combine: reduce 1024 bce partials + 16 costs
// ---------------------------------------------------------------------------
__global__ __launch_bounds__(256) void k_final(const float* __restrict__ ws,
                                               float* __restrict__ out) {
  const int tid = threadIdx.x;
  __shared__ float redb[4], redc[4];
  float vb = 0.0f;
#pragma unroll
  for (int i = 0; i < 4; ++i) vb += ws[WS_BCE0 + tid + 256 * i];
  float vc = (tid < NB) ? ws[WS_COST + tid] : 0.0f;
  for (int o = 32; o; o >>= 1) { vb += __shfl_down(vb, o); vc += __shfl_down(vc, o); }
  if ((tid & 63) == 0) { redb[tid >> 6] = vb; redc[tid >> 6] = vc; }
  __syncthreads();
  if (tid == 0) {
    float B = redb[0] + redb[1] + redb[2] + redb[3];
    float C = redc[0] + redc[1] + redc[2] + redc[3];
    out[0] = -B * (1000000.0f / 1048576.0f) + C * (2000.0f / 16.0f);
  }
}

extern "C" void kernel_launch(void* const* d_in, const int* in_sizes, int n_in,
                              void* d_out, int out_size, void* d_ws, size_t ws_size,
                              hipStream_t stream) {
  const float* pred = (const float*)d_in[0];
  const float* targ = (const float*)d_in[1];
  float* ws = (float*)d_ws;
  float* out = (float*)d_out;

  k_main<<<16 + NB * 64, 192, 0, stream>>>(pred, targ, ws);
  k_final<<<1, 256, 0, stream>>>(ws, out);
}

// Round 12
// 26.820 us; speedup vs baseline: 1.7943x; 1.0894x over previous
//
#include <hip/hip_runtime.h>
#include <math.h>

#define NKP 68
#define NB 16
#define SK_ITERS 50

#define INVV 0.03125f                  // 1/(2*sigma^2), sigma=4
#define LOG_A (-4.219507705176107f)    // -log(68)
#define L2E 1.4426950408889634f
#define LN2 0.6931471805599453f
#define KGF (100.0f * L2E)             // (1/eps)*log2(e)
#define SW 40.0f                       // power-of-two shift baked into W
#define WBIAS (L2E * LOG_A + SW)
#define C2X (-INVV * 1.4426950408889634f)  // gaussian exponent, base-2

// workspace float offsets (all plain stores, no init needed)
#define WS_COST 0     // [16]   sinkhorn per-batch cost
#define WS_BCE0 16    // [1024] per-block bce partial sums

typedef float f32x2 __attribute__((ext_vector_type(2)));

__device__ __forceinline__ float E2(float x) {
#if __has_builtin(__builtin_amdgcn_exp2f)
  return __builtin_amdgcn_exp2f(x);
#else
  return exp2f(x);
#endif
}
__device__ __forceinline__ float L2(float x) {
#if __has_builtin(__builtin_amdgcn_logf)
  return __builtin_amdgcn_logf(x);   // v_log_f32 = log2
#else
  return log2f(x);
#endif
}
__device__ __forceinline__ float RCP(float x) {
#if __has_builtin(__builtin_amdgcn_rcpf)
  return __builtin_amdgcn_rcpf(x);   // v_rcp_f32, ~1 ulp
#else
  return 1.0f / x;
#endif
}
__device__ __forceinline__ f32x2 fma2(f32x2 a, f32x2 b, f32x2 c) {
#if __has_builtin(__builtin_elementwise_fma)
  return __builtin_elementwise_fma(a, b, c);   // -> v_pk_fma_f32
#else
  f32x2 r; r.x = fmaf(a.x, b.x, c.x); r.y = fmaf(a.y, b.y, c.y); return r;
#endif
}
// sum over lane pair (DPP quad_perm xor1) — both lanes get the total
__device__ __forceinline__ float dpp_xor1_add(float s) {
#if __has_builtin(__builtin_amdgcn_mov_dpp)
  int t = __builtin_amdgcn_mov_dpp(__float_as_int(s), 0xB1, 0xF, 0xF, true);
  return s + __int_as_float(t);
#else
  return s + __shfl_xor(s, 1);
#endif
}
// W_ij = 2^40 * exp(-C_ij/eps)/N, computed in base 2
__device__ __forceinline__ float wcomp(float2 a, float2 b) {
  float d0 = a.x - b.x, d1 = a.y - b.y;
  return E2(fmaf(-KGF, d0 * d0 + d1 * d1, WBIAS));
}

// token-paste helper so member access stays outside the paste
#define WREG(WP, N) WP##N

// ---------------------------------------------------------------------------
// Sinkhorn in SCALING form: u = 2^40 / (W v), v = 2^40 / (W^T u).
// W held in EXPLICIT named f32x2 registers (no arrays -> no alloca -> no
// scratch). 2 lanes per row, 136 active lanes in 3 waves. Dot = 17
// v_pk_fma_f32 in 4 independent chains (halves VALU issue vs 34 scalar FMAs).
// ---------------------------------------------------------------------------
__device__ void sink_part(const float* __restrict__ pred,
                          const float* __restrict__ targ,
                          float* __restrict__ ws, int b) {
  __shared__ float ush[80], vsh[80], wred[3];
  const int tid = threadIdx.x;
  const bool act = tid < 136;
  const int r = act ? (tid >> 1) : 0;
  const int q = tid & 1;
  const int rb = q * 40;               // LDS read base (16B aligned, groups of 40)
  const int j0 = act ? q * 34 : 0;

  __builtin_amdgcn_s_setprio(1);

  const float2* pc = (const float2*)(pred + b * NKP * 2);
  const float2* tc = (const float2*)(targ + b * NKP * 2);
  const float2 xi = pc[r];   // pred point, f-row r
  const float2 yj = tc[r];   // targ point, g-row r

  // Wf row (vs targ points), Wg row (transpose: pred points vs yj)
  const f32x2 wf0  = {wcomp(xi, tc[j0+ 0]), wcomp(xi, tc[j0+ 1])};
  const f32x2 wf1  = {wcomp(xi, tc[j0+ 2]), wcomp(xi, tc[j0+ 3])};
  const f32x2 wf2  = {wcomp(xi, tc[j0+ 4]), wcomp(xi, tc[j0+ 5])};
  const f32x2 wf3  = {wcomp(xi, tc[j0+ 6]), wcomp(xi, tc[j0+ 7])};
  const f32x2 wf4  = {wcomp(xi, tc[j0+ 8]), wcomp(xi, tc[j0+ 9])};
  const f32x2 wf5  = {wcomp(xi, tc[j0+10]), wcomp(xi, tc[j0+11])};
  const f32x2 wf6  = {wcomp(xi, tc[j0+12]), wcomp(xi, tc[j0+13])};
  const f32x2 wf7  = {wcomp(xi, tc[j0+14]), wcomp(xi, tc[j0+15])};
  const f32x2 wf8  = {wcomp(xi, tc[j0+16]), wcomp(xi, tc[j0+17])};
  const f32x2 wf9  = {wcomp(xi, tc[j0+18]), wcomp(xi, tc[j0+19])};
  const f32x2 wf10 = {wcomp(xi, tc[j0+20]), wcomp(xi, tc[j0+21])};
  const f32x2 wf11 = {wcomp(xi, tc[j0+22]), wcomp(xi, tc[j0+23])};
  const f32x2 wf12 = {wcomp(xi, tc[j0+24]), wcomp(xi, tc[j0+25])};
  const f32x2 wf13 = {wcomp(xi, tc[j0+26]), wcomp(xi, tc[j0+27])};
  const f32x2 wf14 = {wcomp(xi, tc[j0+28]), wcomp(xi, tc[j0+29])};
  const f32x2 wf15 = {wcomp(xi, tc[j0+30]), wcomp(xi, tc[j0+31])};
  const f32x2 wf16 = {wcomp(xi, tc[j0+32]), wcomp(xi, tc[j0+33])};
  const f32x2 wg0  = {wcomp(pc[j0+ 0], yj), wcomp(pc[j0+ 1], yj)};
  const f32x2 wg1  = {wcomp(pc[j0+ 2], yj), wcomp(pc[j0+ 3], yj)};
  const f32x2 wg2  = {wcomp(pc[j0+ 4], yj), wcomp(pc[j0+ 5], yj)};
  const f32x2 wg3  = {wcomp(pc[j0+ 6], yj), wcomp(pc[j0+ 7], yj)};
  const f32x2 wg4  = {wcomp(pc[j0+ 8], yj), wcomp(pc[j0+ 9], yj)};
  const f32x2 wg5  = {wcomp(pc[j0+10], yj), wcomp(pc[j0+11], yj)};
  const f32x2 wg6  = {wcomp(pc[j0+12], yj), wcomp(pc[j0+13], yj)};
  const f32x2 wg7  = {wcomp(pc[j0+14], yj), wcomp(pc[j0+15], yj)};
  const f32x2 wg8  = {wcomp(pc[j0+16], yj), wcomp(pc[j0+17], yj)};
  const f32x2 wg9  = {wcomp(pc[j0+18], yj), wcomp(pc[j0+19], yj)};
  const f32x2 wg10 = {wcomp(pc[j0+20], yj), wcomp(pc[j0+21], yj)};
  const f32x2 wg11 = {wcomp(pc[j0+22], yj), wcomp(pc[j0+23], yj)};
  const f32x2 wg12 = {wcomp(pc[j0+24], yj), wcomp(pc[j0+25], yj)};
  const f32x2 wg13 = {wcomp(pc[j0+26], yj), wcomp(pc[j0+27], yj)};
  const f32x2 wg14 = {wcomp(pc[j0+28], yj), wcomp(pc[j0+29], yj)};
  const f32x2 wg15 = {wcomp(pc[j0+30], yj), wcomp(pc[j0+31], yj)};
  const f32x2 wg16 = {wcomp(pc[j0+32], yj), wcomp(pc[j0+33], yj)};

  const int wofs = (r < 34) ? r : r + 6;   // padded write offset
  if (tid < 80) vsh[tid] = 1.0f;           // v0 = exp(g0/eps) = 1
  __syncthreads();

// 9 wide LDS loads (b128), zero-cost aliased into f32x2 halves; dot as 17
// v_pk_fma_f32 in 4 chains (A,B,C,D), depth 5.
#define SINK_HALF(SRC, DST, WP, RESULT)                                      \
  {                                                                          \
    const float4* gv = (const float4*)&SRC[rb];                              \
    float4 G0 = gv[0], G1 = gv[1], G2 = gv[2], G3 = gv[3];                   \
    float4 G4 = gv[4], G5 = gv[5], G6 = gv[6], G7 = gv[7];                   \
    float2 G8 = *(const float2*)&SRC[rb + 32];                               \
    f32x2 x0 = {G0.x, G0.y}, x1 = {G0.z, G0.w};                              \
    f32x2 x2 = {G1.x, G1.y}, x3 = {G1.z, G1.w};                              \
    f32x2 x4 = {G2.x, G2.y}, x5 = {G2.z, G2.w};                              \
    f32x2 x6 = {G3.x, G3.y}, x7 = {G3.z, G3.w};                              \
    f32x2 x8 = {G4.x, G4.y}, x9 = {G4.z, G4.w};                              \
    f32x2 x10 = {G5.x, G5.y}, x11 = {G5.z, G5.w};                            \
    f32x2 x12 = {G6.x, G6.y}, x13 = {G6.z, G6.w};                            \
    f32x2 x14 = {G7.x, G7.y}, x15 = {G7.z, G7.w};                            \
    f32x2 x16 = {G8.x, G8.y};                                                \
    f32x2 A = WREG(WP,0) * x0;                                               \
    f32x2 Bc = WREG(WP,1) * x1;                                              \
    f32x2 Cc = WREG(WP,2) * x2;                                              \
    f32x2 Dc = WREG(WP,3) * x3;                                              \
    A  = fma2(WREG(WP,4),  x4,  A);  Bc = fma2(WREG(WP,5),  x5,  Bc);        \
    Cc = fma2(WREG(WP,6),  x6,  Cc); Dc = fma2(WREG(WP,7),  x7,  Dc);        \
    A  = fma2(WREG(WP,8),  x8,  A);  Bc = fma2(WREG(WP,9),  x9,  Bc);        \
    Cc = fma2(WREG(WP,10), x10, Cc); Dc = fma2(WREG(WP,11), x11, Dc);        \
    A  = fma2(WREG(WP,12), x12, A);  Bc = fma2(WREG(WP,13), x13, Bc);        \
    Cc = fma2(WREG(WP,14), x14, Cc); Dc = fma2(WREG(WP,15), x15, Dc);        \
    A  = fma2(WREG(WP,16), x16, A);                                          \
    A = A + Bc; Cc = Cc + Dc; A = A + Cc;                                    \
    float s = A.x + A.y;                                                     \
    s = dpp_xor1_add(s);                                                     \
    RESULT = RCP(s) * 0x1p+40f;                                              \
    if (act && q == 0) DST[wofs] = RESULT;                                   \
  }

  float u = 0.0f;
#pragma unroll 1
  for (int it = 0; it < SK_ITERS; ++it) {
    float vdummy;
    SINK_HALF(vsh, ush, wf, u)       // f-half: u = 2^40 / (W v)
    __syncthreads();
    SINK_HALF(ush, vsh, wg, vdummy)  // g-half: v = 2^40 / (W^T u)
    (void)vdummy;
    __syncthreads();
  }

  // cost_b = 2^-40/N * sum_i u_i * sum_j (Wf_ij C_ij) v_j ; C from log2(Wf),
  // underflowed W (==0) contributes exactly 0.
#define CT(w, g) ((w) > 0.0f ? (w) * ((WBIAS - L2(w)) * (1.0f / KGF)) * (g) : 0.0f)
#define CP(W, GX, GY) { c0 += CT(W.x, GX); c1 += CT(W.y, GY); }

  float local = 0.0f;
  {
    const float4* gv = (const float4*)&vsh[rb];
    float4 G0 = gv[0], G1 = gv[1], G2 = gv[2], G3 = gv[3];
    float4 G4 = gv[4], G5 = gv[5], G6 = gv[6], G7 = gv[7];
    float2 G8 = *(const float2*)&vsh[rb + 32];
    float c0 = 0, c1 = 0;
    CP(wf0,  G0.x, G0.y) CP(wf1,  G0.z, G0.w)
    CP(wf2,  G1.x, G1.y) CP(wf3,  G1.z, G1.w)
    CP(wf4,  G2.x, G2.y) CP(wf5,  G2.z, G2.w)
    CP(wf6,  G3.x, G3.y) CP(wf7,  G3.z, G3.w)
    CP(wf8,  G4.x, G4.y) CP(wf9,  G4.z, G4.w)
    CP(wf10, G5.x, G5.y) CP(wf11, G5.z, G5.w)
    CP(wf12, G6.x, G6.y) CP(wf13, G6.z, G6.w)
    CP(wf14, G7.x, G7.y) CP(wf15, G7.z, G7.w)
    CP(wf16, G8.x, G8.y)
    float sc = c0 + c1;
    sc = dpp_xor1_add(sc);
    if (act && q == 0) local = sc * u;
  }
  for (int o = 32; o; o >>= 1) local += __shfl_down(local, o);
  if ((tid & 63) == 0) wred[tid >> 6] = local;
  __syncthreads();
  if (tid == 0)
    ws[WS_COST + b] = (wred[0] + wred[1] + wred[2]) * (0x1p-40f / 68.0f);
  __builtin_amdgcn_s_setprio(0);
}

// ---------------------------------------------------------------------------
// BCE: block = one batch x 8-row y-tile x 128-col x-half. Windowed (40-sample)
// per-axis gaussian sums for normalization; gy staged in LDS; gx recomputed.
// ---------------------------------------------------------------------------
__device__ void bce_part(const float* __restrict__ pred,
                         const float* __restrict__ targ,
                         float* __restrict__ ws, int bidx) {
  __shared__ float ls[4][NKP];
  __shared__ __attribute__((aligned(16))) float gyp8[NKP][8];
  __shared__ __attribute__((aligned(16))) float gyt8[NKP][8];
  __shared__ float pxp_s[NKP], pxt_s[NKP];
  __shared__ float sS[2];
  __shared__ float bred[3];

  const int b = bidx >> 6;
  const int t6 = bidx & 63;
  const int y0 = (t6 >> 1) * 8;
  const int xbase = (t6 & 1) * 128;
  const int tid = threadIdx.x;

  for (int idx = tid; idx < 272; idx += 192) {
    const int n = idx >> 2, slot = idx & 3;          // 0 px,1 py,2 tx,3 ty
    const float* src = (slot < 2) ? pred : targ;
    const float c = src[(b * NKP + n) * 2 + (slot & 1)] * 255.0f;
    int x0 = (int)c - 19;
    x0 = max(0, min(216, x0));
    float g0 = (float)x0 - c, g1 = g0 + 1.0f, g2 = g0 + 2.0f, g3 = g0 + 3.0f;
    float s0 = 0, s1 = 0, s2 = 0, s3 = 0;
#pragma unroll 2
    for (int v = 0; v < 10; ++v) {
      s0 += E2(g0 * g0 * C2X);
      s1 += E2(g1 * g1 * C2X);
      s2 += E2(g2 * g2 * C2X);
      s3 += E2(g3 * g3 * C2X);
      g0 += 4.0f; g1 += 4.0f; g2 += 4.0f; g3 += 4.0f;
    }
    ls[slot][n] = (s0 + s1) + (s2 + s3);
  }
  for (int idx = tid; idx < NKP * 2; idx += 192) {
    const int n = idx >> 1, tsel = idx & 1;
    const float* c = tsel ? targ : pred;
    float v = c[(b * NKP + n) * 2] * 255.0f;
    (tsel ? pxt_s : pxp_s)[n] = v;
  }
  for (int idx = tid; idx < NKP * 16; idx += 192) {
    const int t2 = idx & 1, rr = (idx >> 1) & 7, n = idx >> 4;
    const float* c = t2 ? targ : pred;
    float py = c[(b * NKP + n) * 2 + 1] * 255.0f;
    float dy = (float)(y0 + rr) - py;
    (t2 ? gyt8 : gyp8)[n][rr] = E2(dy * dy * C2X);
  }
  __syncthreads();

  if (tid < 64) {
    float sp = ls[0][tid] * ls[1][tid];
    float st = ls[2][tid] * ls[3][tid];
    if (tid < 4) {
      sp += ls[0][64 + tid] * ls[1][64 + tid];
      st += ls[2][64 + tid] * ls[3][64 + tid];
    }
    for (int o = 32; o; o >>= 1) { sp += __shfl_down(sp, o); st += __shfl_down(st, o); }
    if (tid == 0) { sS[0] = sp; sS[1] = st; }
  }
  __syncthreads();

  float accp[8] = {0, 0, 0, 0, 0, 0, 0, 0};
  float acct[8] = {0, 0, 0, 0, 0, 0, 0, 0};
  if (tid < 128) {
    const float fx = (float)(xbase + tid);
    for (int n = 0; n < NKP; ++n) {
      float dxp = fx - pxp_s[n];
      float gxp = E2(dxp * dxp * C2X);
      float dxt = fx - pxt_s[n];
      float gxt = E2(dxt * dxt * C2X);
      const float4 gp0 = *(const float4*)&gyp8[n][0];
      const float4 gp1 = *(const float4*)&gyp8[n][4];
      const float4 gt0 = *(const float4*)&gyt8[n][0];
      const float4 gt1 = *(const float4*)&gyt8[n][4];
      accp[0] = fmaf(gp0.x, gxp, accp[0]);
      accp[1] = fmaf(gp0.y, gxp, accp[1]);
      accp[2] = fmaf(gp0.z, gxp, accp[2]);
      accp[3] = fmaf(gp0.w, gxp, accp[3]);
      accp[4] = fmaf(gp1.x, gxp, accp[4]);
      accp[5] = fmaf(gp1.y, gxp, accp[5]);
      accp[6] = fmaf(gp1.z, gxp, accp[6]);
      accp[7] = fmaf(gp1.w, gxp, accp[7]);
      acct[0] = fmaf(gt0.x, gxt, acct[0]);
      acct[1] = fmaf(gt0.y, gxt, acct[1]);
      acct[2] = fmaf(gt0.z, gxt, acct[2]);
      acct[3] = fmaf(gt0.w, gxt, acct[3]);
      acct[4] = fmaf(gt1.x, gxt, acct[4]);
      acct[5] = fmaf(gt1.y, gxt, acct[5]);
      acct[6] = fmaf(gt1.z, gxt, acct[6]);
      acct[7] = fmaf(gt1.w, gxt, acct[7]);
    }
  }

  float local = 0.0f;
  if (tid < 128) {
    const float rsp = 1.0f / (sS[0] + 1e-8f);
    const float rst = 1.0f / sS[1];
#pragma unroll
    for (int rr = 0; rr < 8; ++rr) {
      float p = accp[rr] * rsp;
      float t = acct[rr] * rst;
      float lp = fmaxf(LN2 * L2(p), -100.0f);
      float l1 = fmaxf(LN2 * L2(1.0f - p), -100.0f);
      local += t * lp + (1.0f - t) * l1;
    }
  }
  for (int o = 32; o; o >>= 1) local += __shfl_down(local, o);
  if ((tid & 63) == 0) bred[tid >> 6] = local;
  __syncthreads();
  if (tid == 0)
    ws[WS_BCE0 + bidx] = bred[0] + bred[1] + bred[2];   // plain store
}

// ---------------------------------------------------------------------------
// Fused main kernel: blocks 0..15 sinkhorn, 16..1039 BCE.
// ---------------------------------------------------------------------------
__global__ __launch_bounds__(192, 3) void k_main(const float* __restrict__ pred,
                                                 const float* __restrict__ targ,
                                                 float* __restrict__ ws) {
  if (blockIdx.x < 16)
    sink_part(pred, targ, ws, blockIdx.x);
  else
    bce_part(pred, targ, ws, blockIdx.x - 16);
}

// ---------------------------------------------------------------------------
// Final combine: reduce 1024 bce partials + 16 costs
// ---------------------------------------------------------------------------
__global__ __launch_bounds__(256) void k_final(const float* __restrict__ ws,
                                               float* __restrict__ out) {
  const int tid = threadIdx.x;
  __shared__ float redb[4], redc[4];
  float vb = 0.0f;
#pragma unroll
  for (int i = 0; i < 4; ++i) vb += ws[WS_BCE0 + tid + 256 * i];
  float vc = (tid < NB) ? ws[WS_COST + tid] : 0.0f;
  for (int o = 32; o; o >>= 1) { vb += __shfl_down(vb, o); vc += __shfl_down(vc, o); }
  if ((tid & 63) == 0) { redb[tid >> 6] = vb; redc[tid >> 6] = vc; }
  __syncthreads();
  if (tid == 0) {
    float B = redb[0] + redb[1] + redb[2] + redb[3];
    float C = redc[0] + redc[1] + redc[2] + redc[3];
    out[0] = -B * (1000000.0f / 1048576.0f) + C * (2000.0f / 16.0f);
  }
}

extern "C" void kernel_launch(void* const* d_in, const int* in_sizes, int n_in,
                              void* d_out, int out_size, void* d_ws, size_t ws_size,
                              hipStream_t stream) {
  const float* pred = (const float*)d_in[0];
  const float* targ = (const float*)d_in[1];
  float* ws = (float*)d_ws;
  float* out = (float*)d_out;

  k_main<<<16 + NB * 64, 192, 0, stream>>>(pred, targ, ws);
  k_final<<<1, 256, 0, stream>>>(ws, out);
}